// Round 21
// baseline (212.721 us; speedup 1.0000x reference)
//
#include <hip/hip_runtime.h>
#include <hip/hip_bf16.h>

// Problem constants: B=2, S=2048, DIM=2048, H=16, KVH=8, D=128

typedef __attribute__((ext_vector_type(8))) short s16x8;   // 8 bf16 in 4 VGPRs
typedef __attribute__((ext_vector_type(4))) float f32x4;
typedef __attribute__((ext_vector_type(16))) float f32x16;

typedef const __attribute__((address_space(1))) void* gas_t;
typedef __attribute__((address_space(3))) void* las_t;
#define GLL16(g, l) __builtin_amdgcn_global_load_lds((gas_t)(const void*)(g), (las_t)(void*)(l), 16, 0, 0)

static __device__ __forceinline__ unsigned short f2bf(float f) {
    union { float f; unsigned u; } v; v.f = f;
    unsigned r = v.u + 0x7FFF + ((v.u >> 16) & 1);   // RNE
    return (unsigned short)(r >> 16);
}
static __device__ __forceinline__ float bf2f(unsigned short h) {
    union { unsigned u; float f; } v; v.u = ((unsigned)h) << 16;
    return v.f;
}
static __device__ __forceinline__ float exp2_fast(float x) {
    float r; asm("v_exp_f32 %0, %1" : "=v"(r) : "v"(x)); return r;
}
static __device__ __forceinline__ unsigned cvt_pk_bf16(float a, float b) {
    unsigned r; asm("v_cvt_pk_bf16_f32 %0, %1, %2" : "=v"(r) : "v"(a), "v"(b)); return r;
}

// scale(1/sqrt(128)) * log2(e): baked into Q so softmax runs in exp2 domain
#define SCALE_L2E 0.12751744900929f

// ---------------- fused prep: weight transposes (z=0..3, 64x64 tiles) + x convert (z=4) ----------------
__global__ __launch_bounds__(256) void k_prep(const float* __restrict__ x,
                                              const float* __restrict__ wq,
                                              const float* __restrict__ wk,
                                              const float* __restrict__ wv,
                                              const float* __restrict__ wo,
                                              unsigned short* __restrict__ xb,
                                              unsigned short* __restrict__ w1t,
                                              unsigned short* __restrict__ w2t) {
    __shared__ float t[64][65];
    int z = blockIdx.z;
    int tid = threadIdx.x;
    if (z == 4) {   // x -> bf16, 8192 elems per block (4 chunks)
        int bidc = blockIdx.y * 32 + blockIdx.x;   // 0..1023
        #pragma unroll
        for (int j = 0; j < 4; j++) {
            int i = ((bidc * 4 + j) * 256 + tid) * 8;
            float4 a = *(const float4*)(x + i);
            float4 b = *(const float4*)(x + i + 4);
            s16x8 o;
            o[0] = (short)f2bf(a.x); o[1] = (short)f2bf(a.y); o[2] = (short)f2bf(a.z); o[3] = (short)f2bf(a.w);
            o[4] = (short)f2bf(b.x); o[5] = (short)f2bf(b.y); o[6] = (short)f2bf(b.z); o[7] = (short)f2bf(b.w);
            *(s16x8*)(xb + i) = o;
        }
        return;
    }
    const float* src; unsigned short* dst; int N, nbase;
    if (z == 0)      { src = wq; dst = w1t; N = 2048; nbase = 0;    }
    else if (z == 1) { src = wk; dst = w1t; N = 1024; nbase = 2048; }
    else if (z == 2) { src = wv; dst = w1t; N = 1024; nbase = 3072; }
    else             { src = wo; dst = w2t; N = 2048; nbase = 0;    }
    int k0 = blockIdx.x * 64, n0 = blockIdx.y * 64;
    if (n0 >= N) return;
    int tx = tid & 63, ty0 = tid >> 6;
    #pragma unroll
    for (int p = 0; p < 16; p++) {
        int ty = ty0 + p * 4;
        t[ty][tx] = src[(size_t)(k0 + ty) * N + n0 + tx];
    }
    __syncthreads();
    #pragma unroll
    for (int p = 0; p < 16; p++) {
        int ty = ty0 + p * 4;
        dst[(size_t)(nbase + n0 + ty) * 2048 + k0 + tx] = f2bf(t[tx][ty]);   // 128B rows
    }
}

// ---------------- bf16 transpose: V (2048 x 128) -> Vt (128 x 2048), 64x64 tiles ----------------
__global__ __launch_bounds__(256) void k_transpose_v(const unsigned short* __restrict__ V,
                                                     unsigned short* __restrict__ Vt) {
    __shared__ unsigned short t[64][65];
    int s0 = blockIdx.x * 64, d0 = blockIdx.y * 64;
    size_t base = (size_t)blockIdx.z * 2048 * 128;
    int tid = threadIdx.x;
    int tx = tid & 63, ty0 = tid >> 6;
    #pragma unroll
    for (int p = 0; p < 16; p++) {
        int ty = ty0 + p * 4;
        t[ty][tx] = V[base + (size_t)(s0 + ty) * 128 + d0 + tx];
    }
    __syncthreads();
    #pragma unroll
    for (int p = 0; p < 16; p++) {
        int ty = ty0 + p * 4;
        Vt[base + (size_t)(d0 + ty) * 2048 + s0 + tx] = t[tx][ty];   // 128B rows
    }
}

// ---------------- fused QKV GEMM (v5 phases) + RMSNorm + RoPE + head-split epilogue ----------------
// Body identical to gemm256 v5. Epilogue: tile -> LDS (slot-swizzled bf16 [256][256]),
// then 512 threads remap to (row, head): thread-local sum-of-squares, gamma*rsqrt,
// RoPE (partner d+-64 thread-local), coalesced 256B writes to Qt/Kt/Vt. V copies raw.
__global__ __launch_bounds__(512, 2) void k_gemm_qkv(const unsigned short* __restrict__ A,
                                                     const unsigned short* __restrict__ Bt,
                                                     const float* __restrict__ qg,
                                                     const float* __restrict__ kg,
                                                     const float* __restrict__ cosc,
                                                     const float* __restrict__ sinc,
                                                     unsigned short* __restrict__ Qt,
                                                     unsigned short* __restrict__ Kt,
                                                     unsigned short* __restrict__ Vt,
                                                     int K) {
    __shared__ unsigned short Ls[2][2][2][8192];   // [slot][mat][kk][256*32] = 128 KiB
    int tid = threadIdx.x, lane = tid & 63, wave = tid >> 6;
    int wm = wave >> 2, wn = wave & 3;
    int lr = lane & 15, lg = lane >> 4;
    int swrow = wave * 16 + (lane >> 2);
    int scol  = (((lane & 3) ^ ((lane >> 3) & 3)) * 8);
    int cg    = ((lg ^ ((lr >> 1) & 3)) * 8);
    const unsigned short* Ab = A  + (size_t)(blockIdx.x * 256) * K;
    const unsigned short* Bb = Bt + (size_t)(blockIdx.y * 256) * K;

    f32x4 acc[8][4] = {};
    int NK = K / 64;

    auto issue = [&](int slot, int mat, int kk, int k0) {
        const unsigned short* base = mat ? Bb : Ab;
        unsigned short* dst = &Ls[slot][mat][kk][wave * 512];
        GLL16(base + (size_t)swrow * K + k0 + kk * 32 + scol, dst);
        GLL16(base + (size_t)(swrow + 128) * K + k0 + kk * 32 + scol, dst + 4096);
    };

    issue(0, 0, 0, 0);
    issue(0, 1, 0, 0);
    issue(0, 0, 1, 0);
    issue(0, 1, 1, 0);
    asm volatile("s_waitcnt vmcnt(4)" ::: "memory");
    __builtin_amdgcn_s_barrier();

    for (int t = 0; t < NK; ++t) {
        int slot = t & 1, nslot = slot ^ 1;
        int kn = (t + 1) * 64;
        bool more = (t + 1) < NK;
        const unsigned short* As0 = Ls[slot][0][0];
        const unsigned short* Bs0 = Ls[slot][1][0];
        const unsigned short* As1 = Ls[slot][0][1];
        const unsigned short* Bs1 = Ls[slot][1][1];
        s16x8 af[4], bfr[4];

        // ---- phase 0: kk0, m0-3 ----
        #pragma unroll
        for (int m = 0; m < 4; m++) af[m]  = *(const s16x8*)&As0[(wm * 128 + m * 16 + lr) * 32 + cg];
        #pragma unroll
        for (int n = 0; n < 4; n++) bfr[n] = *(const s16x8*)&Bs0[(wn * 64 + n * 16 + lr) * 32 + cg];
        if (more) issue(nslot, 0, 0, kn);
        asm volatile("" ::: "memory");
        __builtin_amdgcn_s_barrier();
        __builtin_amdgcn_s_setprio(1);
        #pragma unroll
        for (int m = 0; m < 4; m++)
            #pragma unroll
            for (int n = 0; n < 4; n++)
                acc[m][n] = __builtin_amdgcn_mfma_f32_16x16x32_bf16(af[m], bfr[n], acc[m][n], 0, 0, 0);
        __builtin_amdgcn_s_setprio(0);
        asm volatile("" ::: "memory");
        __builtin_amdgcn_s_barrier();

        // ---- phase 1: kk0, m4-7 ----
        #pragma unroll
        for (int m = 0; m < 4; m++) af[m] = *(const s16x8*)&As0[(wm * 128 + (m + 4) * 16 + lr) * 32 + cg];
        if (more) { issue(nslot, 1, 0, kn); asm volatile("s_waitcnt vmcnt(4)" ::: "memory"); }
        else      {                         asm volatile("s_waitcnt vmcnt(0)" ::: "memory"); }
        asm volatile("" ::: "memory");
        __builtin_amdgcn_s_barrier();
        __builtin_amdgcn_s_setprio(1);
        #pragma unroll
        for (int m = 0; m < 4; m++)
            #pragma unroll
            for (int n = 0; n < 4; n++)
                acc[m + 4][n] = __builtin_amdgcn_mfma_f32_16x16x32_bf16(af[m], bfr[n], acc[m + 4][n], 0, 0, 0);
        __builtin_amdgcn_s_setprio(0);
        asm volatile("" ::: "memory");
        __builtin_amdgcn_s_barrier();

        // ---- phase 2: kk1, m0-3 ----
        #pragma unroll
        for (int m = 0; m < 4; m++) af[m]  = *(const s16x8*)&As1[(wm * 128 + m * 16 + lr) * 32 + cg];
        #pragma unroll
        for (int n = 0; n < 4; n++) bfr[n] = *(const s16x8*)&Bs1[(wn * 64 + n * 16 + lr) * 32 + cg];
        if (more) issue(nslot, 0, 1, kn);
        asm volatile("" ::: "memory");
        __builtin_amdgcn_s_barrier();
        __builtin_amdgcn_s_setprio(1);
        #pragma unroll
        for (int m = 0; m < 4; m++)
            #pragma unroll
            for (int n = 0; n < 4; n++)
                acc[m][n] = __builtin_amdgcn_mfma_f32_16x16x32_bf16(af[m], bfr[n], acc[m][n], 0, 0, 0);
        __builtin_amdgcn_s_setprio(0);
        asm volatile("" ::: "memory");
        __builtin_amdgcn_s_barrier();

        // ---- phase 3: kk1, m4-7 ----
        #pragma unroll
        for (int m = 0; m < 4; m++) af[m] = *(const s16x8*)&As1[(wm * 128 + (m + 4) * 16 + lr) * 32 + cg];
        if (more) { issue(nslot, 1, 1, kn); asm volatile("s_waitcnt vmcnt(4)" ::: "memory"); }
        asm volatile("" ::: "memory");
        __builtin_amdgcn_s_barrier();
        __builtin_amdgcn_s_setprio(1);
        #pragma unroll
        for (int m = 0; m < 4; m++)
            #pragma unroll
            for (int n = 0; n < 4; n++)
                acc[m + 4][n] = __builtin_amdgcn_mfma_f32_16x16x32_bf16(af[m], bfr[n], acc[m + 4][n], 0, 0, 0);
        __builtin_amdgcn_s_setprio(0);
        asm volatile("" ::: "memory");
        __builtin_amdgcn_s_barrier();
    }

    // ---- fused epilogue ----
    unsigned short* Lc = (unsigned short*)Ls;   // [256 rows][32 slots of 8 elems], slot-swizzled
    #pragma unroll
    for (int am = 0; am < 8; am++)
        #pragma unroll
        for (int n = 0; n < 4; n++)
            #pragma unroll
            for (int r = 0; r < 4; r++) {
                int row_l = wm * 128 + am * 16 + lg * 4 + r;
                int col_l = wn * 64 + n * 16 + lr;
                int cs = (col_l >> 3) ^ (row_l & 15);
                Lc[row_l * 256 + cs * 8 + (col_l & 7)] = f2bf(acc[am][n][r]);
            }
    __syncthreads();
    int row_l = tid & 255;
    int hb = tid >> 8;
    int row_g = blockIdx.x * 256 + row_l;
    int bb = row_g >> 11, s = row_g & 2047;
    int seg = blockIdx.y * 2 + hb;          // 0..15 Q, 16..23 K, 24..31 V
    s16x8 vals[16];
    #pragma unroll
    for (int j = 0; j < 16; j++) {
        int cs = (hb * 16 + j) ^ (row_l & 15);
        vals[j] = *(const s16x8*)&Lc[row_l * 256 + cs * 8];
    }
    if (seg >= 24) {   // V: raw copy
        unsigned short* dst = Vt + ((size_t)(bb * 8 + seg - 24) * 2048 + s) * 128;
        #pragma unroll
        for (int j = 0; j < 16; j++) *(s16x8*)(dst + j * 8) = vals[j];
    } else {
        float ssq = 0.f;
        #pragma unroll
        for (int j = 0; j < 16; j++)
            #pragma unroll
            for (int e = 0; e < 8; e++) { float f = bf2f((unsigned short)vals[j][e]); ssq += f * f; }
        float rn = rsqrtf(ssq * (1.0f / 128.0f) + 1e-6f);
        const float* g = (seg < 16) ? qg : kg;
        float rg = rn * ((seg < 16) ? SCALE_L2E : 1.0f);
        unsigned short* dst = (seg < 16)
            ? Qt + ((size_t)(bb * 16 + seg) * 2048 + s) * 128
            : Kt + ((size_t)(bb * 8 + seg - 16) * 2048 + s) * 128;
        #pragma unroll
        for (int j = 0; j < 8; j++) {
            float4 gl0 = *(const float4*)(g + j * 8);
            float4 gl1 = *(const float4*)(g + j * 8 + 4);
            float4 gh0 = *(const float4*)(g + 64 + j * 8);
            float4 gh1 = *(const float4*)(g + 64 + j * 8 + 4);
            float4 c0  = *(const float4*)(cosc + (size_t)s * 64 + j * 8);
            float4 c1  = *(const float4*)(cosc + (size_t)s * 64 + j * 8 + 4);
            float4 sn0 = *(const float4*)(sinc + (size_t)s * 64 + j * 8);
            float4 sn1 = *(const float4*)(sinc + (size_t)s * 64 + j * 8 + 4);
            float glv[8] = {gl0.x, gl0.y, gl0.z, gl0.w, gl1.x, gl1.y, gl1.z, gl1.w};
            float ghv[8] = {gh0.x, gh0.y, gh0.z, gh0.w, gh1.x, gh1.y, gh1.z, gh1.w};
            float cv[8]  = {c0.x, c0.y, c0.z, c0.w, c1.x, c1.y, c1.z, c1.w};
            float sv[8]  = {sn0.x, sn0.y, sn0.z, sn0.w, sn1.x, sn1.y, sn1.z, sn1.w};
            s16x8 ol, oh;
            #pragma unroll
            for (int e = 0; e < 8; e++) {
                float tl = bf2f((unsigned short)vals[j][e])     * rg * glv[e];
                float th = bf2f((unsigned short)vals[j + 8][e]) * rg * ghv[e];
                ol[e] = (short)f2bf(tl * cv[e] - th * sv[e]);
                oh[e] = (short)f2bf(th * cv[e] + tl * sv[e]);
            }
            *(s16x8*)(dst + j * 8)      = ol;
            *(s16x8*)(dst + 64 + j * 8) = oh;
        }
    }
}

// ---------------- 128x128 GEMM, v5 phase structure (for gemm2), R17-verified ----------------
template<int OUTF32>
__global__ __launch_bounds__(256, 2) void k_gemm128(const unsigned short* __restrict__ A,
                                                    const unsigned short* __restrict__ Bt,
                                                    void* __restrict__ Cout,
                                                    int M, int N, int K) {
    __shared__ unsigned short Ls[2][2][2][4096];   // [slot][mat][kk][128*32] = 64 KiB
    int tid = threadIdx.x, lane = tid & 63, wave = tid >> 6;
    int wm = wave >> 1, wn = wave & 1;
    int lr = lane & 15, lg = lane >> 4;
    int swrow = wave * 16 + (lane >> 2);
    int scol  = (((lane & 3) ^ ((lane >> 3) & 3)) * 8);
    int cg    = ((lg ^ ((lr >> 1) & 3)) * 8);
    const unsigned short* Ab = A  + (size_t)(blockIdx.x * 128) * K;
    const unsigned short* Bb = Bt + (size_t)(blockIdx.y * 128) * K;

    f32x4 acc[4][4] = {};
    int NK = K / 64;

    auto issue = [&](int slot, int mat, int kk, int k0) {
        const unsigned short* base = mat ? Bb : Ab;
        unsigned short* dst = &Ls[slot][mat][kk][wave * 512];
        GLL16(base + (size_t)swrow * K + k0 + kk * 32 + scol, dst);
        GLL16(base + (size_t)(swrow + 64) * K + k0 + kk * 32 + scol, dst + 2048);
    };

    issue(0, 0, 0, 0);
    issue(0, 1, 0, 0);
    issue(0, 0, 1, 0);
    issue(0, 1, 1, 0);
    asm volatile("s_waitcnt vmcnt(4)" ::: "memory");
    __builtin_amdgcn_s_barrier();

    for (int t = 0; t < NK; ++t) {
        int slot = t & 1, nslot = slot ^ 1;
        int kn = (t + 1) * 64;
        bool more = (t + 1) < NK;
        const unsigned short* As0 = Ls[slot][0][0];
        const unsigned short* Bs0 = Ls[slot][1][0];
        const unsigned short* As1 = Ls[slot][0][1];
        const unsigned short* Bs1 = Ls[slot][1][1];
        s16x8 af[4], bfr[4];

        // ---- phase 0: kk0 (certified). Issue kk0(t+1); vmcnt certifies kk1(t). ----
        #pragma unroll
        for (int m = 0; m < 4; m++) af[m]  = *(const s16x8*)&As0[(wm * 64 + m * 16 + lr) * 32 + cg];
        #pragma unroll
        for (int n = 0; n < 4; n++) bfr[n] = *(const s16x8*)&Bs0[(wn * 64 + n * 16 + lr) * 32 + cg];
        if (more) { issue(nslot, 0, 0, kn); issue(nslot, 1, 0, kn);
                    asm volatile("s_waitcnt vmcnt(4)" ::: "memory"); }
        else      { asm volatile("s_waitcnt vmcnt(0)" ::: "memory"); }
        asm volatile("" ::: "memory");
        __builtin_amdgcn_s_barrier();
        __builtin_amdgcn_s_setprio(1);
        #pragma unroll
        for (int m = 0; m < 4; m++)
            #pragma unroll
            for (int n = 0; n < 4; n++)
                acc[m][n] = __builtin_amdgcn_mfma_f32_16x16x32_bf16(af[m], bfr[n], acc[m][n], 0, 0, 0);
        __builtin_amdgcn_s_setprio(0);
        asm volatile("" ::: "memory");
        __builtin_amdgcn_s_barrier();

        // ---- phase 1: kk1 (certified by ph0). Issue kk1(t+1); vmcnt certifies kk0(t+1). ----
        #pragma unroll
        for (int m = 0; m < 4; m++) af[m]  = *(const s16x8*)&As1[(wm * 64 + m * 16 + lr) * 32 + cg];
        #pragma unroll
        for (int n = 0; n < 4; n++) bfr[n] = *(const s16x8*)&Bs1[(wn * 64 + n * 16 + lr) * 32 + cg];
        if (more) { issue(nslot, 0, 1, kn); issue(nslot, 1, 1, kn);
                    asm volatile("s_waitcnt vmcnt(4)" ::: "memory"); }
        asm volatile("" ::: "memory");
        __builtin_amdgcn_s_barrier();
        __builtin_amdgcn_s_setprio(1);
        #pragma unroll
        for (int m = 0; m < 4; m++)
            #pragma unroll
            for (int n = 0; n < 4; n++)
                acc[m][n] = __builtin_amdgcn_mfma_f32_16x16x32_bf16(af[m], bfr[n], acc[m][n], 0, 0, 0);
        __builtin_amdgcn_s_setprio(0);
        asm volatile("" ::: "memory");
        __builtin_amdgcn_s_barrier();
    }

    int rbase = blockIdx.x * 128 + wm * 64;
    int cbase = blockIdx.y * 128 + wn * 64;
    #pragma unroll
    for (int m = 0; m < 4; m++)
        #pragma unroll
        for (int n = 0; n < 4; n++)
            #pragma unroll
            for (int r = 0; r < 4; r++) {
                int row = rbase + m * 16 + lg * 4 + r;
                int col = cbase + n * 16 + lr;
                float v = acc[m][n][r];
                if (OUTF32) ((float*)Cout)[(size_t)row * N + col] = v;
                else        ((unsigned short*)Cout)[(size_t)row * N + col] = f2bf(v);
            }
}

// ---------------- causal GQA flash attention: GLL-staged dbuf K/V + in-register P ----------------
__global__ __launch_bounds__(256, 2) void k_attn(const unsigned short* __restrict__ Qt,
                                                 const unsigned short* __restrict__ Kt,
                                                 const unsigned short* __restrict__ Vtg,
                                                 unsigned short* __restrict__ attn) {
    __shared__ unsigned short Ks[2][64 * 128];   // [buf][kv][d] swizzled  32 KiB
    __shared__ unsigned short Vs[2][128 * 64];   // [buf][d][kv] swizzled  32 KiB
    int bid = blockIdx.x;                  // 0..511
    int lo = bid & 255;
    int qb, bh;
    if (bid < 256) { qb = lo & 15;        bh = lo >> 4; }
    else           { qb = 15 - (lo & 15); bh = 16 + (lo >> 4); }
    int b = bh >> 4, h = bh & 15;
    int kvh = h >> 1;
    int tid = threadIdx.x;
    int lane = tid & 63, wave = tid >> 6;
    int ql = lane & 31;                    // q-local (wave's 32 rows)
    int hf = lane >> 5;                    // half 0/1
    int q0 = qb * 128;
    const unsigned short* Qb    = Qt + ((size_t)bh * 2048 + q0 + wave * 32 + ql) * 128;
    const unsigned short* Kbase = Kt + (size_t)(b * 8 + kvh) * 2048 * 128;
    const unsigned short* Vtb   = Vtg + (size_t)(b * 8 + kvh) * 128 * 2048;   // [d][s]
    s16x8 aq[8];
    #pragma unroll
    for (int ds = 0; ds < 8; ds++)
        aq[ds] = *(const s16x8*)(Qb + ds * 16 + hf * 8);
    f32x16 out[4] = {};
    float m_q = -1e30f, l_q = 0.f;
    int qglob = q0 + wave * 32 + ql;
    int qlo   = q0 + wave * 32;            // wave-uniform bounds
    int qhi   = qlo + 31;
    int ntiles = 2 * qb + 2;
    int krow = tid >> 4, kcolb = tid & 15;
    int vrow = tid >> 3, vcolb = tid & 7;
    int kscol = (kcolb ^ (krow & 7)) * 8;   // pre-swizzled global source col (elems)
    int vscol = (vcolb ^ (vrow & 7)) * 8;
    int eq = (ql & 7);                      // read-side swizzle base

    auto stage = [&](int buf, int k0) {     // 8 GLL: dest linear (= tid*16B + p*4KB)
        #pragma unroll
        for (int p = 0; p < 4; p++) {
            GLL16(Kbase + (size_t)(k0 + krow + p * 16) * 128 + kscol,
                  &Ks[buf][(krow + p * 16) * 128 + kcolb * 8]);
            GLL16(Vtb + (size_t)(vrow + p * 32) * 2048 + k0 + vscol,
                  &Vs[buf][(vrow + p * 32) * 64 + vcolb * 8]);
        }
    };

    stage(0, 0);   // prologue: tile 0

    for (int t = 0; t < ntiles; t++) {
        int k0 = t * 64;
        int buf = t & 1;
        asm volatile("s_waitcnt vmcnt(0)" ::: "memory");   // tile t landed
        __syncthreads();                                   // cross-wave visibility / WAR
        if (t + 1 < ntiles) stage(buf ^ 1, k0 + 64);       // async, lands under compute
        if (k0 <= qhi) {
            f32x16 st[2] = {};
            __builtin_amdgcn_s_setprio(1);
            #pragma unroll
            for (int sub = 0; sub < 2; sub++)
                #pragma unroll
                for (int ds = 0; ds < 8; ds++) {
                    s16x8 kf = *(const s16x8*)&Ks[buf][(sub * 32 + ql) * 128 + ((ds * 2 + hf) ^ eq) * 8];
                    st[sub] = __builtin_amdgcn_mfma_f32_32x32x16_bf16(kf, aq[ds], st[sub], 0, 0, 0);
                }
            __builtin_amdgcn_s_setprio(0);
            float mx = -1e30f;
            if (k0 + 63 > qlo) {
                #pragma unroll
                for (int sub = 0; sub < 2; sub++)
                    #pragma unroll
                    for (int r = 0; r < 16; r++) {
                        int kv = k0 + sub * 32 + (r & 3) + 8 * (r >> 2) + 4 * hf;
                        if (kv > qglob) st[sub][r] = -1e30f;
                        mx = fmaxf(mx, st[sub][r]);
                    }
            } else {
                #pragma unroll
                for (int sub = 0; sub < 2; sub++)
                    #pragma unroll
                    for (int r = 0; r < 16; r++) mx = fmaxf(mx, st[sub][r]);
            }
            mx = fmaxf(mx, __shfl_xor(mx, 32, 64));
            bool defer = __all(mx <= m_q + 8.0f);
            float sf = 1.0f;
            if (!defer) {
                float mnew = fmaxf(m_q, mx);
                sf = exp2_fast(m_q - mnew);
                m_q = mnew;
            }
            float rs = 0.f;
            #pragma unroll
            for (int sub = 0; sub < 2; sub++)
                #pragma unroll
                for (int r = 0; r < 16; r++) {
                    float e = exp2_fast(st[sub][r] - m_q);
                    st[sub][r] = e;
                    rs += e;
                }
            rs += __shfl_xor(rs, 32, 64);
            l_q = defer ? (l_q + rs) : (l_q * sf + rs);
            // in-register P fragments: cvt_pk + permlane32_swap (T12)
            s16x8 pf[4];
            #pragma unroll
            for (int sub = 0; sub < 2; sub++) {
                unsigned w0a = cvt_pk_bf16(st[sub][0],  st[sub][1]);
                unsigned w0b = cvt_pk_bf16(st[sub][2],  st[sub][3]);
                unsigned w1a = cvt_pk_bf16(st[sub][4],  st[sub][5]);
                unsigned w1b = cvt_pk_bf16(st[sub][6],  st[sub][7]);
                unsigned w2a = cvt_pk_bf16(st[sub][8],  st[sub][9]);
                unsigned w2b = cvt_pk_bf16(st[sub][10], st[sub][11]);
                unsigned w3a = cvt_pk_bf16(st[sub][12], st[sub][13]);
                unsigned w3b = cvt_pk_bf16(st[sub][14], st[sub][15]);
                auto s0 = __builtin_amdgcn_permlane32_swap(w0a, w1a, false, false);
                auto s1 = __builtin_amdgcn_permlane32_swap(w0b, w1b, false, false);
                auto s2 = __builtin_amdgcn_permlane32_swap(w2a, w3a, false, false);
                auto s3 = __builtin_amdgcn_permlane32_swap(w2b, w3b, false, false);
                union { unsigned u[4]; s16x8 v; } fa, fb;
                fa.u[0] = s0[0]; fa.u[1] = s1[0]; fa.u[2] = s0[1]; fa.u[3] = s1[1];
                fb.u[0] = s2[0]; fb.u[1] = s3[0]; fb.u[2] = s2[1]; fb.u[3] = s3[1];
                pf[sub * 2]     = fa.v;
                pf[sub * 2 + 1] = fb.v;
            }
            if (!defer) {
                float sfr[16];
                #pragma unroll
                for (int r = 0; r < 16; r++)
                    sfr[r] = __shfl(sf, (r & 3) + 8 * (r >> 2) + 4 * hf, 64);
                #pragma unroll
                for (int dblk = 0; dblk < 4; dblk++)
                    #pragma unroll
                    for (int r = 0; r < 16; r++) out[dblk][r] *= sfr[r];
            }
            __builtin_amdgcn_s_setprio(1);
            #pragma unroll
            for (int ks = 0; ks < 4; ks++) {
                #pragma unroll
                for (int dblk = 0; dblk < 4; dblk++) {
                    s16x8 vf = *(const s16x8*)&Vs[buf][(dblk * 32 + ql) * 64 + ((ks * 2 + hf) ^ eq) * 8];
                    out[dblk] = __builtin_amdgcn_mfma_f32_32x32x16_bf16(pf[ks], vf, out[dblk], 0, 0, 0);
                }
            }
            __builtin_amdgcn_s_setprio(0);
        }
    }
    float linv = 1.0f / l_q;
    float inv[16];
    #pragma unroll
    for (int r = 0; r < 16; r++)
        inv[r] = __shfl(linv, (r & 3) + 8 * (r >> 2) + 4 * hf, 64);
    #pragma unroll
    for (int dblk = 0; dblk < 4; dblk++)
        #pragma unroll
        for (int r = 0; r < 16; r++) {
            int row = q0 + wave * 32 + (r & 3) + 8 * (r >> 2) + 4 * hf;
            attn[((size_t)(b * 2048) + row) * 2048 + h * 128 + dblk * 32 + ql] =
                f2bf(out[dblk][r] * inv[r]);
        }
}

extern "C" void kernel_launch(void* const* d_in, const int* in_sizes, int n_in,
                              void* d_out, int out_size, void* d_ws, size_t ws_size,
                              hipStream_t stream) {
    const float* x    = (const float*)d_in[0];
    const float* wq   = (const float*)d_in[1];
    const float* wk   = (const float*)d_in[2];
    const float* wv   = (const float*)d_in[3];
    const float* wo   = (const float*)d_in[4];
    const float* qg   = (const float*)d_in[5];
    const float* kg   = (const float*)d_in[6];
    const float* cosc = (const float*)d_in[7];
    const float* sinc = (const float*)d_in[8];

    char* ws = (char*)d_ws;
    unsigned short* xb   = (unsigned short*)(ws);                 // 16 MiB  x bf16 (4096x2048)
    unsigned short* w1t  = (unsigned short*)(ws + 16777216);      // 16 MiB  [wq|wk|wv]^T (4096x2048)
    unsigned short* w2t  = (unsigned short*)(ws + 33554432);      //  8 MiB  wo^T (2048x2048)
    unsigned short* Vtg  = (unsigned short*)(ws + 41943040);      //  8 MiB  (2,8,128,2048)
    unsigned short* Qt   = (unsigned short*)(ws + 75497472);      // 16 MiB  (2,16,2048,128)
    unsigned short* Kt   = (unsigned short*)(ws + 92274688);      //  8 MiB  (2,8,2048,128)
    unsigned short* Vt   = (unsigned short*)(ws + 100663296);     //  8 MiB  (2,8,2048,128)
    unsigned short* attn = (unsigned short*)(ws + 109051904);     // 16 MiB  (4096x2048)

    k_prep<<<dim3(32, 32, 5), 256, 0, stream>>>(x, wq, wk, wv, wo, xb, w1t, w2t);
    k_gemm_qkv<<<dim3(16, 16), 512, 0, stream>>>(xb, w1t, qg, kg, cosc, sinc, Qt, Kt, Vt, 2048);
    k_transpose_v<<<dim3(32, 2, 16), 256, 0, stream>>>(Vt, Vtg);
    k_attn<<<512, 256, 0, stream>>>(Qt, Kt, Vtg, attn);
    k_gemm128<1><<<dim3(32, 16), 256, 0, stream>>>(attn, w2t, d_out, 4096, 2048, 2048);
}

// Round 22
// 205.455 us; speedup vs baseline: 1.0354x; 1.0354x over previous
//
#include <hip/hip_runtime.h>
#include <hip/hip_bf16.h>

// Problem constants: B=2, S=2048, DIM=2048, H=16, KVH=8, D=128

typedef __attribute__((ext_vector_type(8))) short s16x8;   // 8 bf16 in 4 VGPRs
typedef __attribute__((ext_vector_type(4))) float f32x4;
typedef __attribute__((ext_vector_type(16))) float f32x16;

typedef const __attribute__((address_space(1))) void* gas_t;
typedef __attribute__((address_space(3))) void* las_t;
#define GLL16(g, l) __builtin_amdgcn_global_load_lds((gas_t)(const void*)(g), (las_t)(void*)(l), 16, 0, 0)

static __device__ __forceinline__ unsigned short f2bf(float f) {
    union { float f; unsigned u; } v; v.f = f;
    unsigned r = v.u + 0x7FFF + ((v.u >> 16) & 1);   // RNE
    return (unsigned short)(r >> 16);
}
static __device__ __forceinline__ float bf2f(unsigned short h) {
    union { unsigned u; float f; } v; v.u = ((unsigned)h) << 16;
    return v.f;
}
static __device__ __forceinline__ float exp2_fast(float x) {
    float r; asm("v_exp_f32 %0, %1" : "=v"(r) : "v"(x)); return r;
}
static __device__ __forceinline__ unsigned cvt_pk_bf16(float a, float b) {
    unsigned r; asm("v_cvt_pk_bf16_f32 %0, %1, %2" : "=v"(r) : "v"(a), "v"(b)); return r;
}

// scale(1/sqrt(128)) * log2(e): baked into Q so softmax runs in exp2 domain
#define SCALE_L2E 0.12751744900929f

// ---------------- fused prep: weight transposes (z=0..3, 64x64 tiles) + x convert (z=4) ----------------
__global__ __launch_bounds__(256) void k_prep(const float* __restrict__ x,
                                              const float* __restrict__ wq,
                                              const float* __restrict__ wk,
                                              const float* __restrict__ wv,
                                              const float* __restrict__ wo,
                                              unsigned short* __restrict__ xb,
                                              unsigned short* __restrict__ w1t,
                                              unsigned short* __restrict__ w2t) {
    __shared__ float t[64][65];
    int z = blockIdx.z;
    int tid = threadIdx.x;
    if (z == 4) {   // x -> bf16, 8192 elems per block (4 chunks)
        int bidc = blockIdx.y * 32 + blockIdx.x;   // 0..1023
        #pragma unroll
        for (int j = 0; j < 4; j++) {
            int i = ((bidc * 4 + j) * 256 + tid) * 8;
            float4 a = *(const float4*)(x + i);
            float4 b = *(const float4*)(x + i + 4);
            s16x8 o;
            o[0] = (short)f2bf(a.x); o[1] = (short)f2bf(a.y); o[2] = (short)f2bf(a.z); o[3] = (short)f2bf(a.w);
            o[4] = (short)f2bf(b.x); o[5] = (short)f2bf(b.y); o[6] = (short)f2bf(b.z); o[7] = (short)f2bf(b.w);
            *(s16x8*)(xb + i) = o;
        }
        return;
    }
    const float* src; unsigned short* dst; int N, nbase;
    if (z == 0)      { src = wq; dst = w1t; N = 2048; nbase = 0;    }
    else if (z == 1) { src = wk; dst = w1t; N = 1024; nbase = 2048; }
    else if (z == 2) { src = wv; dst = w1t; N = 1024; nbase = 3072; }
    else             { src = wo; dst = w2t; N = 2048; nbase = 0;    }
    int k0 = blockIdx.x * 64, n0 = blockIdx.y * 64;
    if (n0 >= N) return;
    int tx = tid & 63, ty0 = tid >> 6;
    #pragma unroll
    for (int p = 0; p < 16; p++) {
        int ty = ty0 + p * 4;
        t[ty][tx] = src[(size_t)(k0 + ty) * N + n0 + tx];
    }
    __syncthreads();
    #pragma unroll
    for (int p = 0; p < 16; p++) {
        int ty = ty0 + p * 4;
        dst[(size_t)(nbase + n0 + ty) * 2048 + k0 + tx] = f2bf(t[tx][ty]);   // 128B rows
    }
}

// ---------------- bf16 transpose: V (2048 x 128) -> Vt (128 x 2048), 64x64 tiles ----------------
__global__ __launch_bounds__(256) void k_transpose_v(const unsigned short* __restrict__ V,
                                                     unsigned short* __restrict__ Vt) {
    __shared__ unsigned short t[64][65];
    int s0 = blockIdx.x * 64, d0 = blockIdx.y * 64;
    size_t base = (size_t)blockIdx.z * 2048 * 128;
    int tid = threadIdx.x;
    int tx = tid & 63, ty0 = tid >> 6;
    #pragma unroll
    for (int p = 0; p < 16; p++) {
        int ty = ty0 + p * 4;
        t[ty][tx] = V[base + (size_t)(s0 + ty) * 128 + d0 + tx];
    }
    __syncthreads();
    #pragma unroll
    for (int p = 0; p < 16; p++) {
        int ty = ty0 + p * 4;
        Vt[base + (size_t)(d0 + ty) * 2048 + s0 + tx] = t[tx][ty];   // 128B rows
    }
}

// ---------------- 256x256 GEMM v5 (read-early phases + quad swizzle) ----------------
template<int OUTF32>
__global__ __launch_bounds__(512, 2) void k_gemm256(const unsigned short* __restrict__ A,
                                                    const unsigned short* __restrict__ Bt,
                                                    void* __restrict__ Cout,
                                                    int M, int N, int K) {
    __shared__ unsigned short Ls[2][2][2][8192];   // [slot][mat][kk][256*32] = 128 KiB
    int tid = threadIdx.x, lane = tid & 63, wave = tid >> 6;
    int wm = wave >> 2, wn = wave & 3;
    int lr = lane & 15, lg = lane >> 4;
    int swrow = wave * 16 + (lane >> 2);
    int scol  = (((lane & 3) ^ ((lane >> 3) & 3)) * 8);
    int cg    = ((lg ^ ((lr >> 1) & 3)) * 8);
    const unsigned short* Ab = A  + (size_t)(blockIdx.x * 256) * K;
    const unsigned short* Bb = Bt + (size_t)(blockIdx.y * 256) * K;

    f32x4 acc[8][4] = {};
    int NK = K / 64;

    auto issue = [&](int slot, int mat, int kk, int k0) {
        const unsigned short* base = mat ? Bb : Ab;
        unsigned short* dst = &Ls[slot][mat][kk][wave * 512];
        GLL16(base + (size_t)swrow * K + k0 + kk * 32 + scol, dst);
        GLL16(base + (size_t)(swrow + 128) * K + k0 + kk * 32 + scol, dst + 4096);
    };

    issue(0, 0, 0, 0);
    issue(0, 1, 0, 0);
    issue(0, 0, 1, 0);
    issue(0, 1, 1, 0);
    asm volatile("s_waitcnt vmcnt(4)" ::: "memory");
    __builtin_amdgcn_s_barrier();

    for (int t = 0; t < NK; ++t) {
        int slot = t & 1, nslot = slot ^ 1;
        int kn = (t + 1) * 64;
        bool more = (t + 1) < NK;
        const unsigned short* As0 = Ls[slot][0][0];
        const unsigned short* Bs0 = Ls[slot][1][0];
        const unsigned short* As1 = Ls[slot][0][1];
        const unsigned short* Bs1 = Ls[slot][1][1];
        s16x8 af[4], bfr[4];

        // ---- phase 0: kk0, m0-3 ----
        #pragma unroll
        for (int m = 0; m < 4; m++) af[m]  = *(const s16x8*)&As0[(wm * 128 + m * 16 + lr) * 32 + cg];
        #pragma unroll
        for (int n = 0; n < 4; n++) bfr[n] = *(const s16x8*)&Bs0[(wn * 64 + n * 16 + lr) * 32 + cg];
        if (more) issue(nslot, 0, 0, kn);
        asm volatile("" ::: "memory");
        __builtin_amdgcn_s_barrier();
        __builtin_amdgcn_s_setprio(1);
        #pragma unroll
        for (int m = 0; m < 4; m++)
            #pragma unroll
            for (int n = 0; n < 4; n++)
                acc[m][n] = __builtin_amdgcn_mfma_f32_16x16x32_bf16(af[m], bfr[n], acc[m][n], 0, 0, 0);
        __builtin_amdgcn_s_setprio(0);
        asm volatile("" ::: "memory");
        __builtin_amdgcn_s_barrier();

        // ---- phase 1: kk0, m4-7 ----
        #pragma unroll
        for (int m = 0; m < 4; m++) af[m] = *(const s16x8*)&As0[(wm * 128 + (m + 4) * 16 + lr) * 32 + cg];
        if (more) { issue(nslot, 1, 0, kn); asm volatile("s_waitcnt vmcnt(4)" ::: "memory"); }
        else      {                         asm volatile("s_waitcnt vmcnt(0)" ::: "memory"); }
        asm volatile("" ::: "memory");
        __builtin_amdgcn_s_barrier();
        __builtin_amdgcn_s_setprio(1);
        #pragma unroll
        for (int m = 0; m < 4; m++)
            #pragma unroll
            for (int n = 0; n < 4; n++)
                acc[m + 4][n] = __builtin_amdgcn_mfma_f32_16x16x32_bf16(af[m], bfr[n], acc[m + 4][n], 0, 0, 0);
        __builtin_amdgcn_s_setprio(0);
        asm volatile("" ::: "memory");
        __builtin_amdgcn_s_barrier();

        // ---- phase 2: kk1, m0-3 ----
        #pragma unroll
        for (int m = 0; m < 4; m++) af[m]  = *(const s16x8*)&As1[(wm * 128 + m * 16 + lr) * 32 + cg];
        #pragma unroll
        for (int n = 0; n < 4; n++) bfr[n] = *(const s16x8*)&Bs1[(wn * 64 + n * 16 + lr) * 32 + cg];
        if (more) issue(nslot, 0, 1, kn);
        asm volatile("" ::: "memory");
        __builtin_amdgcn_s_barrier();
        __builtin_amdgcn_s_setprio(1);
        #pragma unroll
        for (int m = 0; m < 4; m++)
            #pragma unroll
            for (int n = 0; n < 4; n++)
                acc[m][n] = __builtin_amdgcn_mfma_f32_16x16x32_bf16(af[m], bfr[n], acc[m][n], 0, 0, 0);
        __builtin_amdgcn_s_setprio(0);
        asm volatile("" ::: "memory");
        __builtin_amdgcn_s_barrier();

        // ---- phase 3: kk1, m4-7 ----
        #pragma unroll
        for (int m = 0; m < 4; m++) af[m] = *(const s16x8*)&As1[(wm * 128 + (m + 4) * 16 + lr) * 32 + cg];
        if (more) { issue(nslot, 1, 1, kn); asm volatile("s_waitcnt vmcnt(4)" ::: "memory"); }
        asm volatile("" ::: "memory");
        __builtin_amdgcn_s_barrier();
        __builtin_amdgcn_s_setprio(1);
        #pragma unroll
        for (int m = 0; m < 4; m++)
            #pragma unroll
            for (int n = 0; n < 4; n++)
                acc[m + 4][n] = __builtin_amdgcn_mfma_f32_16x16x32_bf16(af[m], bfr[n], acc[m + 4][n], 0, 0, 0);
        __builtin_amdgcn_s_setprio(0);
        asm volatile("" ::: "memory");
        __builtin_amdgcn_s_barrier();
    }

    int rbase = blockIdx.x * 256 + wm * 128;
    int cbase = blockIdx.y * 256 + wn * 64;
    #pragma unroll
    for (int am = 0; am < 8; am++)
        #pragma unroll
        for (int n = 0; n < 4; n++)
            #pragma unroll
            for (int r = 0; r < 4; r++) {
                int row = rbase + am * 16 + lg * 4 + r;
                int col = cbase + n * 16 + lr;
                float v = acc[am][n][r];
                if (OUTF32) ((float*)Cout)[(size_t)row * N + col] = v;
                else        ((unsigned short*)Cout)[(size_t)row * N + col] = f2bf(v);
            }
}

// ---------------- 128x128 GEMM, v5 phase structure (for gemm2), R17-verified ----------------
template<int OUTF32>
__global__ __launch_bounds__(256, 2) void k_gemm128(const unsigned short* __restrict__ A,
                                                    const unsigned short* __restrict__ Bt,
                                                    void* __restrict__ Cout,
                                                    int M, int N, int K) {
    __shared__ unsigned short Ls[2][2][2][4096];   // [slot][mat][kk][128*32] = 64 KiB
    int tid = threadIdx.x, lane = tid & 63, wave = tid >> 6;
    int wm = wave >> 1, wn = wave & 1;
    int lr = lane & 15, lg = lane >> 4;
    int swrow = wave * 16 + (lane >> 2);
    int scol  = (((lane & 3) ^ ((lane >> 3) & 3)) * 8);
    int cg    = ((lg ^ ((lr >> 1) & 3)) * 8);
    const unsigned short* Ab = A  + (size_t)(blockIdx.x * 128) * K;
    const unsigned short* Bb = Bt + (size_t)(blockIdx.y * 128) * K;

    f32x4 acc[4][4] = {};
    int NK = K / 64;

    auto issue = [&](int slot, int mat, int kk, int k0) {
        const unsigned short* base = mat ? Bb : Ab;
        unsigned short* dst = &Ls[slot][mat][kk][wave * 512];
        GLL16(base + (size_t)swrow * K + k0 + kk * 32 + scol, dst);
        GLL16(base + (size_t)(swrow + 64) * K + k0 + kk * 32 + scol, dst + 2048);
    };

    issue(0, 0, 0, 0);
    issue(0, 1, 0, 0);
    issue(0, 0, 1, 0);
    issue(0, 1, 1, 0);
    asm volatile("s_waitcnt vmcnt(4)" ::: "memory");
    __builtin_amdgcn_s_barrier();

    for (int t = 0; t < NK; ++t) {
        int slot = t & 1, nslot = slot ^ 1;
        int kn = (t + 1) * 64;
        bool more = (t + 1) < NK;
        const unsigned short* As0 = Ls[slot][0][0];
        const unsigned short* Bs0 = Ls[slot][1][0];
        const unsigned short* As1 = Ls[slot][0][1];
        const unsigned short* Bs1 = Ls[slot][1][1];
        s16x8 af[4], bfr[4];

        // ---- phase 0: kk0 (certified). Issue kk0(t+1); vmcnt certifies kk1(t). ----
        #pragma unroll
        for (int m = 0; m < 4; m++) af[m]  = *(const s16x8*)&As0[(wm * 64 + m * 16 + lr) * 32 + cg];
        #pragma unroll
        for (int n = 0; n < 4; n++) bfr[n] = *(const s16x8*)&Bs0[(wn * 64 + n * 16 + lr) * 32 + cg];
        if (more) { issue(nslot, 0, 0, kn); issue(nslot, 1, 0, kn);
                    asm volatile("s_waitcnt vmcnt(4)" ::: "memory"); }
        else      { asm volatile("s_waitcnt vmcnt(0)" ::: "memory"); }
        asm volatile("" ::: "memory");
        __builtin_amdgcn_s_barrier();
        __builtin_amdgcn_s_setprio(1);
        #pragma unroll
        for (int m = 0; m < 4; m++)
            #pragma unroll
            for (int n = 0; n < 4; n++)
                acc[m][n] = __builtin_amdgcn_mfma_f32_16x16x32_bf16(af[m], bfr[n], acc[m][n], 0, 0, 0);
        __builtin_amdgcn_s_setprio(0);
        asm volatile("" ::: "memory");
        __builtin_amdgcn_s_barrier();

        // ---- phase 1: kk1 (certified by ph0). Issue kk1(t+1); vmcnt certifies kk0(t+1). ----
        #pragma unroll
        for (int m = 0; m < 4; m++) af[m]  = *(const s16x8*)&As1[(wm * 64 + m * 16 + lr) * 32 + cg];
        #pragma unroll
        for (int n = 0; n < 4; n++) bfr[n] = *(const s16x8*)&Bs1[(wn * 64 + n * 16 + lr) * 32 + cg];
        if (more) { issue(nslot, 0, 1, kn); issue(nslot, 1, 1, kn);
                    asm volatile("s_waitcnt vmcnt(4)" ::: "memory"); }
        asm volatile("" ::: "memory");
        __builtin_amdgcn_s_barrier();
        __builtin_amdgcn_s_setprio(1);
        #pragma unroll
        for (int m = 0; m < 4; m++)
            #pragma unroll
            for (int n = 0; n < 4; n++)
                acc[m][n] = __builtin_amdgcn_mfma_f32_16x16x32_bf16(af[m], bfr[n], acc[m][n], 0, 0, 0);
        __builtin_amdgcn_s_setprio(0);
        asm volatile("" ::: "memory");
        __builtin_amdgcn_s_barrier();
    }

    int rbase = blockIdx.x * 128 + wm * 64;
    int cbase = blockIdx.y * 128 + wn * 64;
    #pragma unroll
    for (int m = 0; m < 4; m++)
        #pragma unroll
        for (int n = 0; n < 4; n++)
            #pragma unroll
            for (int r = 0; r < 4; r++) {
                int row = rbase + m * 16 + lg * 4 + r;
                int col = cbase + n * 16 + lr;
                float v = acc[m][n][r];
                if (OUTF32) ((float*)Cout)[(size_t)row * N + col] = v;
                else        ((unsigned short*)Cout)[(size_t)row * N + col] = f2bf(v);
            }
}

// ---------------- fused RMSNorm + RoPE + head transpose (vectorized) ----------------
__global__ __launch_bounds__(256) void k_rms_rope(const unsigned short* __restrict__ qkv,
                                                  const float* __restrict__ qg,
                                                  const float* __restrict__ kg,
                                                  const float* __restrict__ cosc,
                                                  const float* __restrict__ sinc,
                                                  unsigned short* __restrict__ Qt,
                                                  unsigned short* __restrict__ Kt,
                                                  unsigned short* __restrict__ Vt) {
    int r = blockIdx.x;            // b*2048 + s
    int b = r >> 11;
    int s = r & 2047;
    int tid = threadIdx.x;
    int wave = tid >> 6, lane = tid & 63;
    int sl = lane >> 4;            // local segment 0..3
    int li = lane & 15;
    int d0 = li * 8;               // 0..120
    const unsigned short* row = qkv + (size_t)r * 4096;
    #pragma unroll
    for (int p = 0; p < 2; p++) {
        int seg = p * 16 + wave * 4 + sl;   // 0..31, wave-uniform type
        s16x8 raw = *(const s16x8*)(row + seg * 128 + d0);
        if (seg >= 24) {   // V: straight copy (wave-uniform branch)
            *(s16x8*)(Vt + ((size_t)(b * 8 + (seg - 24)) * 2048 + s) * 128 + d0) = raw;
            continue;
        }
        float e[8];
        #pragma unroll
        for (int j = 0; j < 8; j++) e[j] = bf2f((unsigned short)raw[j]);
        float ssq = 0.f;
        #pragma unroll
        for (int j = 0; j < 8; j++) ssq += e[j] * e[j];
        ssq += __shfl_xor(ssq, 1, 64);
        ssq += __shfl_xor(ssq, 2, 64);
        ssq += __shfl_xor(ssq, 4, 64);
        ssq += __shfl_xor(ssq, 8, 64);
        float rn = rsqrtf(ssq * (1.0f / 128.0f) + 1e-6f);
        const float* g = (seg < 16) ? qg : kg;
        float gs = (seg < 16) ? SCALE_L2E : 1.0f;
        float4 g0 = *(const float4*)(g + d0);
        float4 g1 = *(const float4*)(g + d0 + 4);
        float t[8];
        t[0] = e[0] * rn * g0.x * gs; t[1] = e[1] * rn * g0.y * gs;
        t[2] = e[2] * rn * g0.z * gs; t[3] = e[3] * rn * g0.w * gs;
        t[4] = e[4] * rn * g1.x * gs; t[5] = e[5] * rn * g1.y * gs;
        t[6] = e[6] * rn * g1.z * gs; t[7] = e[7] * rn * g1.w * gs;
        float pr[8];
        #pragma unroll
        for (int j = 0; j < 8; j++) pr[j] = __shfl_xor(t[j], 8, 64);
        int didx = d0 & 63;
        float4 c0 = *(const float4*)(cosc + (size_t)s * 64 + didx);
        float4 c1 = *(const float4*)(cosc + (size_t)s * 64 + didx + 4);
        float4 sn0 = *(const float4*)(sinc + (size_t)s * 64 + didx);
        float4 sn1 = *(const float4*)(sinc + (size_t)s * 64 + didx + 4);
        float cv[8] = {c0.x, c0.y, c0.z, c0.w, c1.x, c1.y, c1.z, c1.w};
        float sv[8] = {sn0.x, sn0.y, sn0.z, sn0.w, sn1.x, sn1.y, sn1.z, sn1.w};
        float sgn = (li < 8) ? -1.0f : 1.0f;
        s16x8 o;
        #pragma unroll
        for (int j = 0; j < 8; j++)
            o[j] = (short)f2bf(t[j] * cv[j] + sgn * pr[j] * sv[j]);
        unsigned short* dst = (seg < 16)
            ? Qt + ((size_t)(b * 16 + seg) * 2048 + s) * 128 + d0
            : Kt + ((size_t)(b * 8 + (seg - 16)) * 2048 + s) * 128 + d0;
        *(s16x8*)dst = o;
    }
}

// ---------------- causal GQA flash attention: dbuf K/V + in-register P (R18, measured best) ----------------
__global__ __launch_bounds__(256, 2) void k_attn(const unsigned short* __restrict__ Qt,
                                                 const unsigned short* __restrict__ Kt,
                                                 const unsigned short* __restrict__ Vtg,
                                                 unsigned short* __restrict__ attn) {
    __shared__ unsigned short Ks[2][64 * 128];   // [buf][kv][d] swizzled  32 KiB
    __shared__ unsigned short Vs[2][128 * 64];   // [buf][d][kv] swizzled  32 KiB
    int bid = blockIdx.x;                  // 0..511
    int lo = bid & 255;
    int qb, bh;
    if (bid < 256) { qb = lo & 15;        bh = lo >> 4; }
    else           { qb = 15 - (lo & 15); bh = 16 + (lo >> 4); }
    int b = bh >> 4, h = bh & 15;
    int kvh = h >> 1;
    int tid = threadIdx.x;
    int lane = tid & 63, wave = tid >> 6;
    int ql = lane & 31;                    // q-local (wave's 32 rows)
    int hf = lane >> 5;                    // half 0/1
    int q0 = qb * 128;
    const unsigned short* Qb    = Qt + ((size_t)bh * 2048 + q0 + wave * 32 + ql) * 128;
    const unsigned short* Kbase = Kt + (size_t)(b * 8 + kvh) * 2048 * 128;
    const unsigned short* Vtb   = Vtg + (size_t)(b * 8 + kvh) * 128 * 2048;   // [d][s]
    s16x8 aq[8];
    #pragma unroll
    for (int ds = 0; ds < 8; ds++)
        aq[ds] = *(const s16x8*)(Qb + ds * 16 + hf * 8);
    f32x16 out[4] = {};
    float m_q = -1e30f, l_q = 0.f;
    int qglob = q0 + wave * 32 + ql;
    int qlo   = q0 + wave * 32;            // wave-uniform bounds
    int qhi   = qlo + 31;
    int ntiles = 2 * qb + 2;
    int krow = tid >> 4, kcolb = tid & 15;   // K: 16 rows x 16 slots per pass
    int vrow = tid >> 3, vcolb = tid & 7;    // V^T: 32 rows x 8 slots per pass
    int ksw = kcolb ^ (krow & 7);
    int vsw = vcolb ^ (vrow & 7);
    int eq = (ql & 7);
    s16x8 kpre[4], vpre[4];
    #pragma unroll
    for (int p = 0; p < 4; p++) {
        kpre[p] = *(const s16x8*)(Kbase + (size_t)(krow + p * 16) * 128 + kcolb * 8);
        vpre[p] = *(const s16x8*)(Vtb + (size_t)(vrow + p * 32) * 2048 + vcolb * 8);
    }

    for (int t = 0; t < ntiles; t++) {
        int k0 = t * 64;
        int buf = t & 1;
        #pragma unroll
        for (int p = 0; p < 4; p++) {
            *(s16x8*)&Ks[buf][(krow + p * 16) * 128 + ksw * 8] = kpre[p];
            *(s16x8*)&Vs[buf][(vrow + p * 32) * 64  + vsw * 8] = vpre[p];
        }
        __syncthreads();
        if (t + 1 < ntiles) {
            int kn = k0 + 64;
            #pragma unroll
            for (int p = 0; p < 4; p++) {
                kpre[p] = *(const s16x8*)(Kbase + (size_t)(kn + krow + p * 16) * 128 + kcolb * 8);
                vpre[p] = *(const s16x8*)(Vtb + (size_t)(vrow + p * 32) * 2048 + kn + vcolb * 8);
            }
        }
        if (k0 <= qhi) {
            f32x16 st[2] = {};
            __builtin_amdgcn_s_setprio(1);
            #pragma unroll
            for (int sub = 0; sub < 2; sub++)
                #pragma unroll
                for (int ds = 0; ds < 8; ds++) {
                    s16x8 kf = *(const s16x8*)&Ks[buf][(sub * 32 + ql) * 128 + ((ds * 2 + hf) ^ eq) * 8];
                    st[sub] = __builtin_amdgcn_mfma_f32_32x32x16_bf16(kf, aq[ds], st[sub], 0, 0, 0);
                }
            __builtin_amdgcn_s_setprio(0);
            float mx = -1e30f;
            if (k0 + 63 > qlo) {
                #pragma unroll
                for (int sub = 0; sub < 2; sub++)
                    #pragma unroll
                    for (int r = 0; r < 16; r++) {
                        int kv = k0 + sub * 32 + (r & 3) + 8 * (r >> 2) + 4 * hf;
                        if (kv > qglob) st[sub][r] = -1e30f;
                        mx = fmaxf(mx, st[sub][r]);
                    }
            } else {
                #pragma unroll
                for (int sub = 0; sub < 2; sub++)
                    #pragma unroll
                    for (int r = 0; r < 16; r++) mx = fmaxf(mx, st[sub][r]);
            }
            mx = fmaxf(mx, __shfl_xor(mx, 32, 64));
            bool defer = __all(mx <= m_q + 8.0f);
            float sf = 1.0f;
            if (!defer) {
                float mnew = fmaxf(m_q, mx);
                sf = exp2_fast(m_q - mnew);
                m_q = mnew;
            }
            float rs = 0.f;
            #pragma unroll
            for (int sub = 0; sub < 2; sub++)
                #pragma unroll
                for (int r = 0; r < 16; r++) {
                    float e = exp2_fast(st[sub][r] - m_q);
                    st[sub][r] = e;
                    rs += e;
                }
            rs += __shfl_xor(rs, 32, 64);
            l_q = defer ? (l_q + rs) : (l_q * sf + rs);
            // in-register P fragments: cvt_pk + permlane32_swap (T12)
            s16x8 pf[4];
            #pragma unroll
            for (int sub = 0; sub < 2; sub++) {
                unsigned w0a = cvt_pk_bf16(st[sub][0],  st[sub][1]);
                unsigned w0b = cvt_pk_bf16(st[sub][2],  st[sub][3]);
                unsigned w1a = cvt_pk_bf16(st[sub][4],  st[sub][5]);
                unsigned w1b = cvt_pk_bf16(st[sub][6],  st[sub][7]);
                unsigned w2a = cvt_pk_bf16(st[sub][8],  st[sub][9]);
                unsigned w2b = cvt_pk_bf16(st[sub][10], st[sub][11]);
                unsigned w3a = cvt_pk_bf16(st[sub][12], st[sub][13]);
                unsigned w3b = cvt_pk_bf16(st[sub][14], st[sub][15]);
                auto s0 = __builtin_amdgcn_permlane32_swap(w0a, w1a, false, false);
                auto s1 = __builtin_amdgcn_permlane32_swap(w0b, w1b, false, false);
                auto s2 = __builtin_amdgcn_permlane32_swap(w2a, w3a, false, false);
                auto s3 = __builtin_amdgcn_permlane32_swap(w2b, w3b, false, false);
                union { unsigned u[4]; s16x8 v; } fa, fb;
                fa.u[0] = s0[0]; fa.u[1] = s1[0]; fa.u[2] = s0[1]; fa.u[3] = s1[1];
                fb.u[0] = s2[0]; fb.u[1] = s3[0]; fb.u[2] = s2[1]; fb.u[3] = s3[1];
                pf[sub * 2]     = fa.v;
                pf[sub * 2 + 1] = fb.v;
            }
            if (!defer) {
                float sfr[16];
                #pragma unroll
                for (int r = 0; r < 16; r++)
                    sfr[r] = __shfl(sf, (r & 3) + 8 * (r >> 2) + 4 * hf, 64);
                #pragma unroll
                for (int dblk = 0; dblk < 4; dblk++)
                    #pragma unroll
                    for (int r = 0; r < 16; r++) out[dblk][r] *= sfr[r];
            }
            __builtin_amdgcn_s_setprio(1);
            #pragma unroll
            for (int ks = 0; ks < 4; ks++) {
                #pragma unroll
                for (int dblk = 0; dblk < 4; dblk++) {
                    s16x8 vf = *(const s16x8*)&Vs[buf][(dblk * 32 + ql) * 64 + ((ks * 2 + hf) ^ eq) * 8];
                    out[dblk] = __builtin_amdgcn_mfma_f32_32x32x16_bf16(pf[ks], vf, out[dblk], 0, 0, 0);
                }
            }
            __builtin_amdgcn_s_setprio(0);
        }
    }
    float linv = 1.0f / l_q;
    float inv[16];
    #pragma unroll
    for (int r = 0; r < 16; r++)
        inv[r] = __shfl(linv, (r & 3) + 8 * (r >> 2) + 4 * hf, 64);
    #pragma unroll
    for (int dblk = 0; dblk < 4; dblk++)
        #pragma unroll
        for (int r = 0; r < 16; r++) {
            int row = q0 + wave * 32 + (r & 3) + 8 * (r >> 2) + 4 * hf;
            attn[((size_t)(b * 2048) + row) * 2048 + h * 128 + dblk * 32 + ql] =
                f2bf(out[dblk][r] * inv[r]);
        }
}

extern "C" void kernel_launch(void* const* d_in, const int* in_sizes, int n_in,
                              void* d_out, int out_size, void* d_ws, size_t ws_size,
                              hipStream_t stream) {
    const float* x    = (const float*)d_in[0];
    const float* wq   = (const float*)d_in[1];
    const float* wk   = (const float*)d_in[2];
    const float* wv   = (const float*)d_in[3];
    const float* wo   = (const float*)d_in[4];
    const float* qg   = (const float*)d_in[5];
    const float* kg   = (const float*)d_in[6];
    const float* cosc = (const float*)d_in[7];
    const float* sinc = (const float*)d_in[8];

    char* ws = (char*)d_ws;
    unsigned short* xb   = (unsigned short*)(ws);                 // 16 MiB  x bf16 (4096x2048)
    unsigned short* w1t  = (unsigned short*)(ws + 16777216);      // 16 MiB  [wq|wk|wv]^T (4096x2048)
    unsigned short* w2t  = (unsigned short*)(ws + 33554432);      //  8 MiB  wo^T (2048x2048)
    unsigned short* qkv  = (unsigned short*)(ws + 41943040);      // 32 MiB  (4096x4096); dead after k_rms_rope
    unsigned short* Qt   = (unsigned short*)(ws + 75497472);      // 16 MiB  (2,16,2048,128)
    unsigned short* Kt   = (unsigned short*)(ws + 92274688);      //  8 MiB  (2,8,2048,128)
    unsigned short* Vt   = (unsigned short*)(ws + 100663296);     //  8 MiB  (2,8,2048,128)
    unsigned short* attn = (unsigned short*)(ws + 109051904);     // 16 MiB  (4096x2048)
    unsigned short* Vtg  = qkv;                                   //  8 MiB  (2,8,128,2048) reuses qkv

    k_prep<<<dim3(32, 32, 5), 256, 0, stream>>>(x, wq, wk, wv, wo, xb, w1t, w2t);
    k_gemm256<0><<<dim3(16, 16), 512, 0, stream>>>(xb, w1t, qkv, 4096, 4096, 2048);
    k_rms_rope<<<4096, 256, 0, stream>>>(qkv, qg, kg, cosc, sinc, Qt, Kt, Vt);
    k_transpose_v<<<dim3(32, 2, 16), 256, 0, stream>>>(Vt, Vtg);
    k_attn<<<512, 256, 0, stream>>>(Qt, Kt, Vtg, attn);
    k_gemm128<1><<<dim3(32, 16), 256, 0, stream>>>(attn, w2t, d_out, 4096, 2048, 2048);
}

// Round 23
// 201.720 us; speedup vs baseline: 1.0545x; 1.0185x over previous
//
#include <hip/hip_runtime.h>
#include <hip/hip_bf16.h>

// Problem constants: B=2, S=2048, DIM=2048, H=16, KVH=8, D=128

typedef __attribute__((ext_vector_type(8))) short s16x8;   // 8 bf16 in 4 VGPRs
typedef __attribute__((ext_vector_type(4))) float f32x4;
typedef __attribute__((ext_vector_type(16))) float f32x16;

typedef const __attribute__((address_space(1))) void* gas_t;
typedef __attribute__((address_space(3))) void* las_t;
#define GLL16(g, l) __builtin_amdgcn_global_load_lds((gas_t)(const void*)(g), (las_t)(void*)(l), 16, 0, 0)

static __device__ __forceinline__ unsigned short f2bf(float f) {
    union { float f; unsigned u; } v; v.f = f;
    unsigned r = v.u + 0x7FFF + ((v.u >> 16) & 1);   // RNE
    return (unsigned short)(r >> 16);
}
static __device__ __forceinline__ float bf2f(unsigned short h) {
    union { unsigned u; float f; } v; v.u = ((unsigned)h) << 16;
    return v.f;
}
static __device__ __forceinline__ float exp2_fast(float x) {
    float r; asm("v_exp_f32 %0, %1" : "=v"(r) : "v"(x)); return r;
}
static __device__ __forceinline__ unsigned cvt_pk_bf16(float a, float b) {
    unsigned r; asm("v_cvt_pk_bf16_f32 %0, %1, %2" : "=v"(r) : "v"(a), "v"(b)); return r;
}

// scale(1/sqrt(128)) * log2(e): baked into Q so softmax runs in exp2 domain
#define SCALE_L2E 0.12751744900929f

// ---------------- fused prep: weight transposes (z=0..3, 64x64 tiles) + x convert (z=4) ----------------
__global__ __launch_bounds__(256) void k_prep(const float* __restrict__ x,
                                              const float* __restrict__ wq,
                                              const float* __restrict__ wk,
                                              const float* __restrict__ wv,
                                              const float* __restrict__ wo,
                                              unsigned short* __restrict__ xb,
                                              unsigned short* __restrict__ w1t,
                                              unsigned short* __restrict__ w2t) {
    __shared__ float t[64][65];
    int z = blockIdx.z;
    int tid = threadIdx.x;
    if (z == 4) {   // x -> bf16, 8192 elems per block (4 chunks)
        int bidc = blockIdx.y * 32 + blockIdx.x;   // 0..1023
        #pragma unroll
        for (int j = 0; j < 4; j++) {
            int i = ((bidc * 4 + j) * 256 + tid) * 8;
            float4 a = *(const float4*)(x + i);
            float4 b = *(const float4*)(x + i + 4);
            s16x8 o;
            o[0] = (short)f2bf(a.x); o[1] = (short)f2bf(a.y); o[2] = (short)f2bf(a.z); o[3] = (short)f2bf(a.w);
            o[4] = (short)f2bf(b.x); o[5] = (short)f2bf(b.y); o[6] = (short)f2bf(b.z); o[7] = (short)f2bf(b.w);
            *(s16x8*)(xb + i) = o;
        }
        return;
    }
    const float* src; unsigned short* dst; int N, nbase;
    if (z == 0)      { src = wq; dst = w1t; N = 2048; nbase = 0;    }
    else if (z == 1) { src = wk; dst = w1t; N = 1024; nbase = 2048; }
    else if (z == 2) { src = wv; dst = w1t; N = 1024; nbase = 3072; }
    else             { src = wo; dst = w2t; N = 2048; nbase = 0;    }
    int k0 = blockIdx.x * 64, n0 = blockIdx.y * 64;
    if (n0 >= N) return;
    int tx = tid & 63, ty0 = tid >> 6;
    #pragma unroll
    for (int p = 0; p < 16; p++) {
        int ty = ty0 + p * 4;
        t[ty][tx] = src[(size_t)(k0 + ty) * N + n0 + tx];
    }
    __syncthreads();
    #pragma unroll
    for (int p = 0; p < 16; p++) {
        int ty = ty0 + p * 4;
        dst[(size_t)(nbase + n0 + ty) * 2048 + k0 + tx] = f2bf(t[tx][ty]);   // 128B rows
    }
}

// ---------------- bf16 transpose: V cols of qkv (s x d, ld 4096) -> Vtg (d x s), 64x64 tiles ----------------
__global__ __launch_bounds__(256) void k_transpose_v(const unsigned short* __restrict__ qkv,
                                                     unsigned short* __restrict__ Vtg) {
    __shared__ unsigned short t[64][65];
    int s0 = blockIdx.x * 64, d0 = blockIdx.y * 64;
    int bkv = blockIdx.z;                    // b*8 + kvh
    int b = bkv >> 3, kvh = bkv & 7;
    const unsigned short* src = qkv + (size_t)(b * 2048) * 4096 + 3072 + kvh * 128;
    unsigned short* dst = Vtg + (size_t)bkv * 128 * 2048;
    int tid = threadIdx.x;
    int tx = tid & 63, ty0 = tid >> 6;
    #pragma unroll
    for (int p = 0; p < 16; p++) {
        int ty = ty0 + p * 4;
        t[ty][tx] = src[(size_t)(s0 + ty) * 4096 + d0 + tx];
    }
    __syncthreads();
    #pragma unroll
    for (int p = 0; p < 16; p++) {
        int ty = ty0 + p * 4;
        dst[(size_t)(d0 + ty) * 2048 + s0 + tx] = t[tx][ty];   // 128B rows
    }
}

// ---------------- 256x256 GEMM v5 (read-early phases + quad swizzle) ----------------
template<int OUTF32>
__global__ __launch_bounds__(512, 2) void k_gemm256(const unsigned short* __restrict__ A,
                                                    const unsigned short* __restrict__ Bt,
                                                    void* __restrict__ Cout,
                                                    int M, int N, int K) {
    __shared__ unsigned short Ls[2][2][2][8192];   // [slot][mat][kk][256*32] = 128 KiB
    int tid = threadIdx.x, lane = tid & 63, wave = tid >> 6;
    int wm = wave >> 2, wn = wave & 3;
    int lr = lane & 15, lg = lane >> 4;
    int swrow = wave * 16 + (lane >> 2);
    int scol  = (((lane & 3) ^ ((lane >> 3) & 3)) * 8);
    int cg    = ((lg ^ ((lr >> 1) & 3)) * 8);
    const unsigned short* Ab = A  + (size_t)(blockIdx.x * 256) * K;
    const unsigned short* Bb = Bt + (size_t)(blockIdx.y * 256) * K;

    f32x4 acc[8][4] = {};
    int NK = K / 64;

    auto issue = [&](int slot, int mat, int kk, int k0) {
        const unsigned short* base = mat ? Bb : Ab;
        unsigned short* dst = &Ls[slot][mat][kk][wave * 512];
        GLL16(base + (size_t)swrow * K + k0 + kk * 32 + scol, dst);
        GLL16(base + (size_t)(swrow + 128) * K + k0 + kk * 32 + scol, dst + 4096);
    };

    issue(0, 0, 0, 0);
    issue(0, 1, 0, 0);
    issue(0, 0, 1, 0);
    issue(0, 1, 1, 0);
    asm volatile("s_waitcnt vmcnt(4)" ::: "memory");
    __builtin_amdgcn_s_barrier();

    for (int t = 0; t < NK; ++t) {
        int slot = t & 1, nslot = slot ^ 1;
        int kn = (t + 1) * 64;
        bool more = (t + 1) < NK;
        const unsigned short* As0 = Ls[slot][0][0];
        const unsigned short* Bs0 = Ls[slot][1][0];
        const unsigned short* As1 = Ls[slot][0][1];
        const unsigned short* Bs1 = Ls[slot][1][1];
        s16x8 af[4], bfr[4];

        // ---- phase 0: kk0, m0-3 ----
        #pragma unroll
        for (int m = 0; m < 4; m++) af[m]  = *(const s16x8*)&As0[(wm * 128 + m * 16 + lr) * 32 + cg];
        #pragma unroll
        for (int n = 0; n < 4; n++) bfr[n] = *(const s16x8*)&Bs0[(wn * 64 + n * 16 + lr) * 32 + cg];
        if (more) issue(nslot, 0, 0, kn);
        asm volatile("" ::: "memory");
        __builtin_amdgcn_s_barrier();
        __builtin_amdgcn_s_setprio(1);
        #pragma unroll
        for (int m = 0; m < 4; m++)
            #pragma unroll
            for (int n = 0; n < 4; n++)
                acc[m][n] = __builtin_amdgcn_mfma_f32_16x16x32_bf16(af[m], bfr[n], acc[m][n], 0, 0, 0);
        __builtin_amdgcn_s_setprio(0);
        asm volatile("" ::: "memory");
        __builtin_amdgcn_s_barrier();

        // ---- phase 1: kk0, m4-7 ----
        #pragma unroll
        for (int m = 0; m < 4; m++) af[m] = *(const s16x8*)&As0[(wm * 128 + (m + 4) * 16 + lr) * 32 + cg];
        if (more) { issue(nslot, 1, 0, kn); asm volatile("s_waitcnt vmcnt(4)" ::: "memory"); }
        else      {                         asm volatile("s_waitcnt vmcnt(0)" ::: "memory"); }
        asm volatile("" ::: "memory");
        __builtin_amdgcn_s_barrier();
        __builtin_amdgcn_s_setprio(1);
        #pragma unroll
        for (int m = 0; m < 4; m++)
            #pragma unroll
            for (int n = 0; n < 4; n++)
                acc[m + 4][n] = __builtin_amdgcn_mfma_f32_16x16x32_bf16(af[m], bfr[n], acc[m + 4][n], 0, 0, 0);
        __builtin_amdgcn_s_setprio(0);
        asm volatile("" ::: "memory");
        __builtin_amdgcn_s_barrier();

        // ---- phase 2: kk1, m0-3 ----
        #pragma unroll
        for (int m = 0; m < 4; m++) af[m]  = *(const s16x8*)&As1[(wm * 128 + m * 16 + lr) * 32 + cg];
        #pragma unroll
        for (int n = 0; n < 4; n++) bfr[n] = *(const s16x8*)&Bs1[(wn * 64 + n * 16 + lr) * 32 + cg];
        if (more) issue(nslot, 0, 1, kn);
        asm volatile("" ::: "memory");
        __builtin_amdgcn_s_barrier();
        __builtin_amdgcn_s_setprio(1);
        #pragma unroll
        for (int m = 0; m < 4; m++)
            #pragma unroll
            for (int n = 0; n < 4; n++)
                acc[m][n] = __builtin_amdgcn_mfma_f32_16x16x32_bf16(af[m], bfr[n], acc[m][n], 0, 0, 0);
        __builtin_amdgcn_s_setprio(0);
        asm volatile("" ::: "memory");
        __builtin_amdgcn_s_barrier();

        // ---- phase 3: kk1, m4-7 ----
        #pragma unroll
        for (int m = 0; m < 4; m++) af[m] = *(const s16x8*)&As1[(wm * 128 + (m + 4) * 16 + lr) * 32 + cg];
        if (more) { issue(nslot, 1, 1, kn); asm volatile("s_waitcnt vmcnt(4)" ::: "memory"); }
        asm volatile("" ::: "memory");
        __builtin_amdgcn_s_barrier();
        __builtin_amdgcn_s_setprio(1);
        #pragma unroll
        for (int m = 0; m < 4; m++)
            #pragma unroll
            for (int n = 0; n < 4; n++)
                acc[m + 4][n] = __builtin_amdgcn_mfma_f32_16x16x32_bf16(af[m], bfr[n], acc[m + 4][n], 0, 0, 0);
        __builtin_amdgcn_s_setprio(0);
        asm volatile("" ::: "memory");
        __builtin_amdgcn_s_barrier();
    }

    int rbase = blockIdx.x * 256 + wm * 128;
    int cbase = blockIdx.y * 256 + wn * 64;
    #pragma unroll
    for (int am = 0; am < 8; am++)
        #pragma unroll
        for (int n = 0; n < 4; n++)
            #pragma unroll
            for (int r = 0; r < 4; r++) {
                int row = rbase + am * 16 + lg * 4 + r;
                int col = cbase + n * 16 + lr;
                float v = acc[am][n][r];
                if (OUTF32) ((float*)Cout)[(size_t)row * N + col] = v;
                else        ((unsigned short*)Cout)[(size_t)row * N + col] = f2bf(v);
            }
}

// ---------------- 128x128 GEMM, v5 phase structure (for gemm2), R17-verified ----------------
template<int OUTF32>
__global__ __launch_bounds__(256, 2) void k_gemm128(const unsigned short* __restrict__ A,
                                                    const unsigned short* __restrict__ Bt,
                                                    void* __restrict__ Cout,
                                                    int M, int N, int K) {
    __shared__ unsigned short Ls[2][2][2][4096];   // [slot][mat][kk][128*32] = 64 KiB
    int tid = threadIdx.x, lane = tid & 63, wave = tid >> 6;
    int wm = wave >> 1, wn = wave & 1;
    int lr = lane & 15, lg = lane >> 4;
    int swrow = wave * 16 + (lane >> 2);
    int scol  = (((lane & 3) ^ ((lane >> 3) & 3)) * 8);
    int cg    = ((lg ^ ((lr >> 1) & 3)) * 8);
    const unsigned short* Ab = A  + (size_t)(blockIdx.x * 128) * K;
    const unsigned short* Bb = Bt + (size_t)(blockIdx.y * 128) * K;

    f32x4 acc[4][4] = {};
    int NK = K / 64;

    auto issue = [&](int slot, int mat, int kk, int k0) {
        const unsigned short* base = mat ? Bb : Ab;
        unsigned short* dst = &Ls[slot][mat][kk][wave * 512];
        GLL16(base + (size_t)swrow * K + k0 + kk * 32 + scol, dst);
        GLL16(base + (size_t)(swrow + 64) * K + k0 + kk * 32 + scol, dst + 2048);
    };

    issue(0, 0, 0, 0);
    issue(0, 1, 0, 0);
    issue(0, 0, 1, 0);
    issue(0, 1, 1, 0);
    asm volatile("s_waitcnt vmcnt(4)" ::: "memory");
    __builtin_amdgcn_s_barrier();

    for (int t = 0; t < NK; ++t) {
        int slot = t & 1, nslot = slot ^ 1;
        int kn = (t + 1) * 64;
        bool more = (t + 1) < NK;
        const unsigned short* As0 = Ls[slot][0][0];
        const unsigned short* Bs0 = Ls[slot][1][0];
        const unsigned short* As1 = Ls[slot][0][1];
        const unsigned short* Bs1 = Ls[slot][1][1];
        s16x8 af[4], bfr[4];

        // ---- phase 0: kk0 (certified). Issue kk0(t+1); vmcnt certifies kk1(t). ----
        #pragma unroll
        for (int m = 0; m < 4; m++) af[m]  = *(const s16x8*)&As0[(wm * 64 + m * 16 + lr) * 32 + cg];
        #pragma unroll
        for (int n = 0; n < 4; n++) bfr[n] = *(const s16x8*)&Bs0[(wn * 64 + n * 16 + lr) * 32 + cg];
        if (more) { issue(nslot, 0, 0, kn); issue(nslot, 1, 0, kn);
                    asm volatile("s_waitcnt vmcnt(4)" ::: "memory"); }
        else      { asm volatile("s_waitcnt vmcnt(0)" ::: "memory"); }
        asm volatile("" ::: "memory");
        __builtin_amdgcn_s_barrier();
        __builtin_amdgcn_s_setprio(1);
        #pragma unroll
        for (int m = 0; m < 4; m++)
            #pragma unroll
            for (int n = 0; n < 4; n++)
                acc[m][n] = __builtin_amdgcn_mfma_f32_16x16x32_bf16(af[m], bfr[n], acc[m][n], 0, 0, 0);
        __builtin_amdgcn_s_setprio(0);
        asm volatile("" ::: "memory");
        __builtin_amdgcn_s_barrier();

        // ---- phase 1: kk1 (certified by ph0). Issue kk1(t+1); vmcnt certifies kk0(t+1). ----
        #pragma unroll
        for (int m = 0; m < 4; m++) af[m]  = *(const s16x8*)&As1[(wm * 64 + m * 16 + lr) * 32 + cg];
        #pragma unroll
        for (int n = 0; n < 4; n++) bfr[n] = *(const s16x8*)&Bs1[(wn * 64 + n * 16 + lr) * 32 + cg];
        if (more) { issue(nslot, 0, 1, kn); issue(nslot, 1, 1, kn);
                    asm volatile("s_waitcnt vmcnt(4)" ::: "memory"); }
        asm volatile("" ::: "memory");
        __builtin_amdgcn_s_barrier();
        __builtin_amdgcn_s_setprio(1);
        #pragma unroll
        for (int m = 0; m < 4; m++)
            #pragma unroll
            for (int n = 0; n < 4; n++)
                acc[m][n] = __builtin_amdgcn_mfma_f32_16x16x32_bf16(af[m], bfr[n], acc[m][n], 0, 0, 0);
        __builtin_amdgcn_s_setprio(0);
        asm volatile("" ::: "memory");
        __builtin_amdgcn_s_barrier();
    }

    int rbase = blockIdx.x * 128 + wm * 64;
    int cbase = blockIdx.y * 128 + wn * 64;
    #pragma unroll
    for (int m = 0; m < 4; m++)
        #pragma unroll
        for (int n = 0; n < 4; n++)
            #pragma unroll
            for (int r = 0; r < 4; r++) {
                int row = rbase + m * 16 + lg * 4 + r;
                int col = cbase + n * 16 + lr;
                float v = acc[m][n][r];
                if (OUTF32) ((float*)Cout)[(size_t)row * N + col] = v;
                else        ((unsigned short*)Cout)[(size_t)row * N + col] = f2bf(v);
            }
}

// ---------------- fused RMSNorm + RoPE + head transpose (Q/K only; V handled by transpose_v) ----------------
__global__ __launch_bounds__(256) void k_rms_rope(const unsigned short* __restrict__ qkv,
                                                  const float* __restrict__ qg,
                                                  const float* __restrict__ kg,
                                                  const float* __restrict__ cosc,
                                                  const float* __restrict__ sinc,
                                                  unsigned short* __restrict__ Qt,
                                                  unsigned short* __restrict__ Kt) {
    int r = blockIdx.x;            // b*2048 + s
    int b = r >> 11;
    int s = r & 2047;
    int tid = threadIdx.x;
    int wave = tid >> 6, lane = tid & 63;
    int sl = lane >> 4;            // local segment 0..3
    int li = lane & 15;
    int d0 = li * 8;               // 0..120
    const unsigned short* row = qkv + (size_t)r * 4096;
    #pragma unroll
    for (int p = 0; p < 2; p++) {
        int seg = p * 16 + wave * 4 + sl;   // 0..31, wave-uniform
        if (seg >= 24) continue;            // V handled elsewhere
        s16x8 raw = *(const s16x8*)(row + seg * 128 + d0);
        float e[8];
        #pragma unroll
        for (int j = 0; j < 8; j++) e[j] = bf2f((unsigned short)raw[j]);
        float ssq = 0.f;
        #pragma unroll
        for (int j = 0; j < 8; j++) ssq += e[j] * e[j];
        ssq += __shfl_xor(ssq, 1, 64);
        ssq += __shfl_xor(ssq, 2, 64);
        ssq += __shfl_xor(ssq, 4, 64);
        ssq += __shfl_xor(ssq, 8, 64);
        float rn = rsqrtf(ssq * (1.0f / 128.0f) + 1e-6f);
        const float* g = (seg < 16) ? qg : kg;
        float gs = (seg < 16) ? SCALE_L2E : 1.0f;
        float4 g0 = *(const float4*)(g + d0);
        float4 g1 = *(const float4*)(g + d0 + 4);
        float t[8];
        t[0] = e[0] * rn * g0.x * gs; t[1] = e[1] * rn * g0.y * gs;
        t[2] = e[2] * rn * g0.z * gs; t[3] = e[3] * rn * g0.w * gs;
        t[4] = e[4] * rn * g1.x * gs; t[5] = e[5] * rn * g1.y * gs;
        t[6] = e[6] * rn * g1.z * gs; t[7] = e[7] * rn * g1.w * gs;
        float pr[8];
        #pragma unroll
        for (int j = 0; j < 8; j++) pr[j] = __shfl_xor(t[j], 8, 64);
        int didx = d0 & 63;
        float4 c0 = *(const float4*)(cosc + (size_t)s * 64 + didx);
        float4 c1 = *(const float4*)(cosc + (size_t)s * 64 + didx + 4);
        float4 sn0 = *(const float4*)(sinc + (size_t)s * 64 + didx);
        float4 sn1 = *(const float4*)(sinc + (size_t)s * 64 + didx + 4);
        float cv[8] = {c0.x, c0.y, c0.z, c0.w, c1.x, c1.y, c1.z, c1.w};
        float sv[8] = {sn0.x, sn0.y, sn0.z, sn0.w, sn1.x, sn1.y, sn1.z, sn1.w};
        float sgn = (li < 8) ? -1.0f : 1.0f;
        s16x8 o;
        #pragma unroll
        for (int j = 0; j < 8; j++)
            o[j] = (short)f2bf(t[j] * cv[j] + sgn * pr[j] * sv[j]);
        unsigned short* dst = (seg < 16)
            ? Qt + ((size_t)(b * 16 + seg) * 2048 + s) * 128 + d0
            : Kt + ((size_t)(b * 8 + (seg - 16)) * 2048 + s) * 128 + d0;
        *(s16x8*)dst = o;
    }
}

// ---------------- causal GQA flash attention: dbuf K/V + in-register P (R18/R21, measured best) ----------------
__global__ __launch_bounds__(256, 2) void k_attn(const unsigned short* __restrict__ Qt,
                                                 const unsigned short* __restrict__ Kt,
                                                 const unsigned short* __restrict__ Vtg,
                                                 unsigned short* __restrict__ attn) {
    __shared__ unsigned short Ks[2][64 * 128];   // [buf][kv][d] swizzled  32 KiB
    __shared__ unsigned short Vs[2][128 * 64];   // [buf][d][kv] swizzled  32 KiB
    int bid = blockIdx.x;                  // 0..511
    int lo = bid & 255;
    int qb, bh;
    if (bid < 256) { qb = lo & 15;        bh = lo >> 4; }
    else           { qb = 15 - (lo & 15); bh = 16 + (lo >> 4); }
    int b = bh >> 4, h = bh & 15;
    int kvh = h >> 1;
    int tid = threadIdx.x;
    int lane = tid & 63, wave = tid >> 6;
    int ql = lane & 31;                    // q-local (wave's 32 rows)
    int hf = lane >> 5;                    // half 0/1
    int q0 = qb * 128;
    const unsigned short* Qb    = Qt + ((size_t)bh * 2048 + q0 + wave * 32 + ql) * 128;
    const unsigned short* Kbase = Kt + (size_t)(b * 8 + kvh) * 2048 * 128;
    const unsigned short* Vtb   = Vtg + (size_t)(b * 8 + kvh) * 128 * 2048;   // [d][s]
    s16x8 aq[8];
    #pragma unroll
    for (int ds = 0; ds < 8; ds++)
        aq[ds] = *(const s16x8*)(Qb + ds * 16 + hf * 8);
    f32x16 out[4] = {};
    float m_q = -1e30f, l_q = 0.f;
    int qglob = q0 + wave * 32 + ql;
    int qlo   = q0 + wave * 32;            // wave-uniform bounds
    int qhi   = qlo + 31;
    int ntiles = 2 * qb + 2;
    int krow = tid >> 4, kcolb = tid & 15;   // K: 16 rows x 16 slots per pass
    int vrow = tid >> 3, vcolb = tid & 7;    // V^T: 32 rows x 8 slots per pass
    int ksw = kcolb ^ (krow & 7);
    int vsw = vcolb ^ (vrow & 7);
    int eq = (ql & 7);
    s16x8 kpre[4], vpre[4];
    #pragma unroll
    for (int p = 0; p < 4; p++) {
        kpre[p] = *(const s16x8*)(Kbase + (size_t)(krow + p * 16) * 128 + kcolb * 8);
        vpre[p] = *(const s16x8*)(Vtb + (size_t)(vrow + p * 32) * 2048 + vcolb * 8);
    }

    for (int t = 0; t < ntiles; t++) {
        int k0 = t * 64;
        int buf = t & 1;
        #pragma unroll
        for (int p = 0; p < 4; p++) {
            *(s16x8*)&Ks[buf][(krow + p * 16) * 128 + ksw * 8] = kpre[p];
            *(s16x8*)&Vs[buf][(vrow + p * 32) * 64  + vsw * 8] = vpre[p];
        }
        __syncthreads();
        if (t + 1 < ntiles) {
            int kn = k0 + 64;
            #pragma unroll
            for (int p = 0; p < 4; p++) {
                kpre[p] = *(const s16x8*)(Kbase + (size_t)(kn + krow + p * 16) * 128 + kcolb * 8);
                vpre[p] = *(const s16x8*)(Vtb + (size_t)(vrow + p * 32) * 2048 + kn + vcolb * 8);
            }
        }
        if (k0 <= qhi) {
            f32x16 st[2] = {};
            __builtin_amdgcn_s_setprio(1);
            #pragma unroll
            for (int sub = 0; sub < 2; sub++)
                #pragma unroll
                for (int ds = 0; ds < 8; ds++) {
                    s16x8 kf = *(const s16x8*)&Ks[buf][(sub * 32 + ql) * 128 + ((ds * 2 + hf) ^ eq) * 8];
                    st[sub] = __builtin_amdgcn_mfma_f32_32x32x16_bf16(kf, aq[ds], st[sub], 0, 0, 0);
                }
            __builtin_amdgcn_s_setprio(0);
            float mx = -1e30f;
            if (k0 + 63 > qlo) {
                #pragma unroll
                for (int sub = 0; sub < 2; sub++)
                    #pragma unroll
                    for (int r = 0; r < 16; r++) {
                        int kv = k0 + sub * 32 + (r & 3) + 8 * (r >> 2) + 4 * hf;
                        if (kv > qglob) st[sub][r] = -1e30f;
                        mx = fmaxf(mx, st[sub][r]);
                    }
            } else {
                #pragma unroll
                for (int sub = 0; sub < 2; sub++)
                    #pragma unroll
                    for (int r = 0; r < 16; r++) mx = fmaxf(mx, st[sub][r]);
            }
            mx = fmaxf(mx, __shfl_xor(mx, 32, 64));
            bool defer = __all(mx <= m_q + 8.0f);
            float sf = 1.0f;
            if (!defer) {
                float mnew = fmaxf(m_q, mx);
                sf = exp2_fast(m_q - mnew);
                m_q = mnew;
            }
            float rs = 0.f;
            #pragma unroll
            for (int sub = 0; sub < 2; sub++)
                #pragma unroll
                for (int r = 0; r < 16; r++) {
                    float e = exp2_fast(st[sub][r] - m_q);
                    st[sub][r] = e;
                    rs += e;
                }
            rs += __shfl_xor(rs, 32, 64);
            l_q = defer ? (l_q + rs) : (l_q * sf + rs);
            // in-register P fragments: cvt_pk + permlane32_swap (T12)
            s16x8 pf[4];
            #pragma unroll
            for (int sub = 0; sub < 2; sub++) {
                unsigned w0a = cvt_pk_bf16(st[sub][0],  st[sub][1]);
                unsigned w0b = cvt_pk_bf16(st[sub][2],  st[sub][3]);
                unsigned w1a = cvt_pk_bf16(st[sub][4],  st[sub][5]);
                unsigned w1b = cvt_pk_bf16(st[sub][6],  st[sub][7]);
                unsigned w2a = cvt_pk_bf16(st[sub][8],  st[sub][9]);
                unsigned w2b = cvt_pk_bf16(st[sub][10], st[sub][11]);
                unsigned w3a = cvt_pk_bf16(st[sub][12], st[sub][13]);
                unsigned w3b = cvt_pk_bf16(st[sub][14], st[sub][15]);
                auto s0 = __builtin_amdgcn_permlane32_swap(w0a, w1a, false, false);
                auto s1 = __builtin_amdgcn_permlane32_swap(w0b, w1b, false, false);
                auto s2 = __builtin_amdgcn_permlane32_swap(w2a, w3a, false, false);
                auto s3 = __builtin_amdgcn_permlane32_swap(w2b, w3b, false, false);
                union { unsigned u[4]; s16x8 v; } fa, fb;
                fa.u[0] = s0[0]; fa.u[1] = s1[0]; fa.u[2] = s0[1]; fa.u[3] = s1[1];
                fb.u[0] = s2[0]; fb.u[1] = s3[0]; fb.u[2] = s2[1]; fb.u[3] = s3[1];
                pf[sub * 2]     = fa.v;
                pf[sub * 2 + 1] = fb.v;
            }
            if (!defer) {
                float sfr[16];
                #pragma unroll
                for (int r = 0; r < 16; r++)
                    sfr[r] = __shfl(sf, (r & 3) + 8 * (r >> 2) + 4 * hf, 64);
                #pragma unroll
                for (int dblk = 0; dblk < 4; dblk++)
                    #pragma unroll
                    for (int r = 0; r < 16; r++) out[dblk][r] *= sfr[r];
            }
            __builtin_amdgcn_s_setprio(1);
            #pragma unroll
            for (int ks = 0; ks < 4; ks++) {
                #pragma unroll
                for (int dblk = 0; dblk < 4; dblk++) {
                    s16x8 vf = *(const s16x8*)&Vs[buf][(dblk * 32 + ql) * 64 + ((ks * 2 + hf) ^ eq) * 8];
                    out[dblk] = __builtin_amdgcn_mfma_f32_32x32x16_bf16(pf[ks], vf, out[dblk], 0, 0, 0);
                }
            }
            __builtin_amdgcn_s_setprio(0);
        }
    }
    float linv = 1.0f / l_q;
    float inv[16];
    #pragma unroll
    for (int r = 0; r < 16; r++)
        inv[r] = __shfl(linv, (r & 3) + 8 * (r >> 2) + 4 * hf, 64);
    #pragma unroll
    for (int dblk = 0; dblk < 4; dblk++)
        #pragma unroll
        for (int r = 0; r < 16; r++) {
            int row = q0 + wave * 32 + (r & 3) + 8 * (r >> 2) + 4 * hf;
            attn[((size_t)(b * 2048) + row) * 2048 + h * 128 + dblk * 32 + ql] =
                f2bf(out[dblk][r] * inv[r]);
        }
}

extern "C" void kernel_launch(void* const* d_in, const int* in_sizes, int n_in,
                              void* d_out, int out_size, void* d_ws, size_t ws_size,
                              hipStream_t stream) {
    const float* x    = (const float*)d_in[0];
    const float* wq   = (const float*)d_in[1];
    const float* wk   = (const float*)d_in[2];
    const float* wv   = (const float*)d_in[3];
    const float* wo   = (const float*)d_in[4];
    const float* qg   = (const float*)d_in[5];
    const float* kg   = (const float*)d_in[6];
    const float* cosc = (const float*)d_in[7];
    const float* sinc = (const float*)d_in[8];

    char* ws = (char*)d_ws;
    unsigned short* xb   = (unsigned short*)(ws);                 // 16 MiB  x bf16 (4096x2048)
    unsigned short* w1t  = (unsigned short*)(ws + 16777216);      // 16 MiB  [wq|wk|wv]^T (4096x2048)
    unsigned short* w2t  = (unsigned short*)(ws + 33554432);      //  8 MiB  wo^T (2048x2048)
    unsigned short* qkv  = (unsigned short*)(ws + 41943040);      // 32 MiB  (4096x4096)
    unsigned short* Qt   = (unsigned short*)(ws + 75497472);      // 16 MiB  (2,16,2048,128)
    unsigned short* Kt   = (unsigned short*)(ws + 92274688);      //  8 MiB  (2,8,2048,128)
    unsigned short* Vtg  = (unsigned short*)(ws + 100663296);     //  8 MiB  (2,8,128,2048)
    unsigned short* attn = (unsigned short*)(ws + 109051904);     // 16 MiB  (4096x2048)

    k_prep<<<dim3(32, 32, 5), 256, 0, stream>>>(x, wq, wk, wv, wo, xb, w1t, w2t);
    k_gemm256<0><<<dim3(16, 16), 512, 0, stream>>>(xb, w1t, qkv, 4096, 4096, 2048);
    k_rms_rope<<<4096, 256, 0, stream>>>(qkv, qg, kg, cosc, sinc, Qt, Kt);
    k_transpose_v<<<dim3(32, 2, 16), 256, 0, stream>>>(qkv, Vtg);
    k_attn<<<512, 256, 0, stream>>>(Qt, Kt, Vtg, attn);
    k_gemm128<1><<<dim3(32, 16), 256, 0, stream>>>(attn, w2t, d_out, 4096, 2048, 2048);
}

// Round 24
// 196.941 us; speedup vs baseline: 1.0801x; 1.0243x over previous
//
#include <hip/hip_runtime.h>
#include <hip/hip_bf16.h>

// Problem constants: B=2, S=2048, DIM=2048, H=16, KVH=8, D=128

typedef __attribute__((ext_vector_type(8))) short s16x8;   // 8 bf16 in 4 VGPRs
typedef __attribute__((ext_vector_type(4))) float f32x4;
typedef __attribute__((ext_vector_type(16))) float f32x16;

typedef const __attribute__((address_space(1))) void* gas_t;
typedef __attribute__((address_space(3))) void* las_t;
#define GLL16(g, l) __builtin_amdgcn_global_load_lds((gas_t)(const void*)(g), (las_t)(void*)(l), 16, 0, 0)

static __device__ __forceinline__ unsigned short f2bf(float f) {
    union { float f; unsigned u; } v; v.f = f;
    unsigned r = v.u + 0x7FFF + ((v.u >> 16) & 1);   // RNE
    return (unsigned short)(r >> 16);
}
static __device__ __forceinline__ float bf2f(unsigned short h) {
    union { unsigned u; float f; } v; v.u = ((unsigned)h) << 16;
    return v.f;
}
static __device__ __forceinline__ float exp2_fast(float x) {
    float r; asm("v_exp_f32 %0, %1" : "=v"(r) : "v"(x)); return r;
}
static __device__ __forceinline__ unsigned cvt_pk_bf16(float a, float b) {
    unsigned r; asm("v_cvt_pk_bf16_f32 %0, %1, %2" : "=v"(r) : "v"(a), "v"(b)); return r;
}

// scale(1/sqrt(128)) * log2(e): baked into Q so softmax runs in exp2 domain
#define SCALE_L2E 0.12751744900929f

// ---------------- fused prep: weight transposes (z=0..3, 64x64 tiles) + x convert (z=4) ----------------
__global__ __launch_bounds__(256) void k_prep(const float* __restrict__ x,
                                              const float* __restrict__ wq,
                                              const float* __restrict__ wk,
                                              const float* __restrict__ wv,
                                              const float* __restrict__ wo,
                                              unsigned short* __restrict__ xb,
                                              unsigned short* __restrict__ w1t,
                                              unsigned short* __restrict__ w2t) {
    __shared__ float t[64][65];
    int z = blockIdx.z;
    int tid = threadIdx.x;
    if (z == 4) {   // x -> bf16, 8192 elems per block (4 chunks)
        int bidc = blockIdx.y * 32 + blockIdx.x;   // 0..1023
        #pragma unroll
        for (int j = 0; j < 4; j++) {
            int i = ((bidc * 4 + j) * 256 + tid) * 8;
            float4 a = *(const float4*)(x + i);
            float4 b = *(const float4*)(x + i + 4);
            s16x8 o;
            o[0] = (short)f2bf(a.x); o[1] = (short)f2bf(a.y); o[2] = (short)f2bf(a.z); o[3] = (short)f2bf(a.w);
            o[4] = (short)f2bf(b.x); o[5] = (short)f2bf(b.y); o[6] = (short)f2bf(b.z); o[7] = (short)f2bf(b.w);
            *(s16x8*)(xb + i) = o;
        }
        return;
    }
    const float* src; unsigned short* dst; int N, nbase;
    if (z == 0)      { src = wq; dst = w1t; N = 2048; nbase = 0;    }
    else if (z == 1) { src = wk; dst = w1t; N = 1024; nbase = 2048; }
    else if (z == 2) { src = wv; dst = w1t; N = 1024; nbase = 3072; }
    else             { src = wo; dst = w2t; N = 2048; nbase = 0;    }
    int k0 = blockIdx.x * 64, n0 = blockIdx.y * 64;
    if (n0 >= N) return;
    int tx = tid & 63, ty0 = tid >> 6;
    #pragma unroll
    for (int p = 0; p < 16; p++) {
        int ty = ty0 + p * 4;
        t[ty][tx] = src[(size_t)(k0 + ty) * N + n0 + tx];
    }
    __syncthreads();
    #pragma unroll
    for (int p = 0; p < 16; p++) {
        int ty = ty0 + p * 4;
        dst[(size_t)(nbase + n0 + ty) * 2048 + k0 + tx] = f2bf(t[tx][ty]);   // 128B rows
    }
}

// ---------------- 256x256 GEMM v5 + XCD cluster swizzle (4x8 clusters per XCD) ----------------
template<int OUTF32>
__global__ __launch_bounds__(512, 2) void k_gemm256(const unsigned short* __restrict__ A,
                                                    const unsigned short* __restrict__ Bt,
                                                    void* __restrict__ Cout,
                                                    int M, int N, int K) {
    __shared__ unsigned short Ls[2][2][2][8192];   // [slot][mat][kk][256*32] = 128 KiB
    int tid = threadIdx.x, lane = tid & 63, wave = tid >> 6;
    int wm = wave >> 2, wn = wave & 3;
    int lr = lane & 15, lg = lane >> 4;
    int swrow = wave * 16 + (lane >> 2);
    int scol  = (((lane & 3) ^ ((lane >> 3) & 3)) * 8);
    int cg    = ((lg ^ ((lr >> 1) & 3)) * 8);
    // XCD cluster swizzle: grid is 16x16 = 256 blocks; XCD = lin%8 (dispatch
    // round-robin); give each XCD a contiguous 4x8 tile cluster (bijective).
    int lin = blockIdx.y * 16 + blockIdx.x;
    int xcd = lin & 7, l = lin >> 3;
    int bx = (xcd & 3) * 4 + (l & 3);
    int by = (xcd >> 2) * 8 + (l >> 2);
    const unsigned short* Ab = A  + (size_t)(bx * 256) * K;
    const unsigned short* Bb = Bt + (size_t)(by * 256) * K;

    f32x4 acc[8][4] = {};
    int NK = K / 64;

    auto issue = [&](int slot, int mat, int kk, int k0) {
        const unsigned short* base = mat ? Bb : Ab;
        unsigned short* dst = &Ls[slot][mat][kk][wave * 512];
        GLL16(base + (size_t)swrow * K + k0 + kk * 32 + scol, dst);
        GLL16(base + (size_t)(swrow + 128) * K + k0 + kk * 32 + scol, dst + 4096);
    };

    issue(0, 0, 0, 0);
    issue(0, 1, 0, 0);
    issue(0, 0, 1, 0);
    issue(0, 1, 1, 0);
    asm volatile("s_waitcnt vmcnt(4)" ::: "memory");
    __builtin_amdgcn_s_barrier();

    for (int t = 0; t < NK; ++t) {
        int slot = t & 1, nslot = slot ^ 1;
        int kn = (t + 1) * 64;
        bool more = (t + 1) < NK;
        const unsigned short* As0 = Ls[slot][0][0];
        const unsigned short* Bs0 = Ls[slot][1][0];
        const unsigned short* As1 = Ls[slot][0][1];
        const unsigned short* Bs1 = Ls[slot][1][1];
        s16x8 af[4], bfr[4];

        // ---- phase 0: kk0, m0-3 ----
        #pragma unroll
        for (int m = 0; m < 4; m++) af[m]  = *(const s16x8*)&As0[(wm * 128 + m * 16 + lr) * 32 + cg];
        #pragma unroll
        for (int n = 0; n < 4; n++) bfr[n] = *(const s16x8*)&Bs0[(wn * 64 + n * 16 + lr) * 32 + cg];
        if (more) issue(nslot, 0, 0, kn);
        asm volatile("" ::: "memory");
        __builtin_amdgcn_s_barrier();
        __builtin_amdgcn_s_setprio(1);
        #pragma unroll
        for (int m = 0; m < 4; m++)
            #pragma unroll
            for (int n = 0; n < 4; n++)
                acc[m][n] = __builtin_amdgcn_mfma_f32_16x16x32_bf16(af[m], bfr[n], acc[m][n], 0, 0, 0);
        __builtin_amdgcn_s_setprio(0);
        asm volatile("" ::: "memory");
        __builtin_amdgcn_s_barrier();

        // ---- phase 1: kk0, m4-7 ----
        #pragma unroll
        for (int m = 0; m < 4; m++) af[m] = *(const s16x8*)&As0[(wm * 128 + (m + 4) * 16 + lr) * 32 + cg];
        if (more) { issue(nslot, 1, 0, kn); asm volatile("s_waitcnt vmcnt(4)" ::: "memory"); }
        else      {                         asm volatile("s_waitcnt vmcnt(0)" ::: "memory"); }
        asm volatile("" ::: "memory");
        __builtin_amdgcn_s_barrier();
        __builtin_amdgcn_s_setprio(1);
        #pragma unroll
        for (int m = 0; m < 4; m++)
            #pragma unroll
            for (int n = 0; n < 4; n++)
                acc[m + 4][n] = __builtin_amdgcn_mfma_f32_16x16x32_bf16(af[m], bfr[n], acc[m + 4][n], 0, 0, 0);
        __builtin_amdgcn_s_setprio(0);
        asm volatile("" ::: "memory");
        __builtin_amdgcn_s_barrier();

        // ---- phase 2: kk1, m0-3 ----
        #pragma unroll
        for (int m = 0; m < 4; m++) af[m]  = *(const s16x8*)&As1[(wm * 128 + m * 16 + lr) * 32 + cg];
        #pragma unroll
        for (int n = 0; n < 4; n++) bfr[n] = *(const s16x8*)&Bs1[(wn * 64 + n * 16 + lr) * 32 + cg];
        if (more) issue(nslot, 0, 1, kn);
        asm volatile("" ::: "memory");
        __builtin_amdgcn_s_barrier();
        __builtin_amdgcn_s_setprio(1);
        #pragma unroll
        for (int m = 0; m < 4; m++)
            #pragma unroll
            for (int n = 0; n < 4; n++)
                acc[m][n] = __builtin_amdgcn_mfma_f32_16x16x32_bf16(af[m], bfr[n], acc[m][n], 0, 0, 0);
        __builtin_amdgcn_s_setprio(0);
        asm volatile("" ::: "memory");
        __builtin_amdgcn_s_barrier();

        // ---- phase 3: kk1, m4-7 ----
        #pragma unroll
        for (int m = 0; m < 4; m++) af[m] = *(const s16x8*)&As1[(wm * 128 + (m + 4) * 16 + lr) * 32 + cg];
        if (more) { issue(nslot, 1, 1, kn); asm volatile("s_waitcnt vmcnt(4)" ::: "memory"); }
        asm volatile("" ::: "memory");
        __builtin_amdgcn_s_barrier();
        __builtin_amdgcn_s_setprio(1);
        #pragma unroll
        for (int m = 0; m < 4; m++)
            #pragma unroll
            for (int n = 0; n < 4; n++)
                acc[m + 4][n] = __builtin_amdgcn_mfma_f32_16x16x32_bf16(af[m], bfr[n], acc[m + 4][n], 0, 0, 0);
        __builtin_amdgcn_s_setprio(0);
        asm volatile("" ::: "memory");
        __builtin_amdgcn_s_barrier();
    }

    int rbase = bx * 256 + wm * 128;
    int cbase = by * 256 + wn * 64;
    #pragma unroll
    for (int am = 0; am < 8; am++)
        #pragma unroll
        for (int n = 0; n < 4; n++)
            #pragma unroll
            for (int r = 0; r < 4; r++) {
                int row = rbase + am * 16 + lg * 4 + r;
                int col = cbase + n * 16 + lr;
                float v = acc[am][n][r];
                if (OUTF32) ((float*)Cout)[(size_t)row * N + col] = v;
                else        ((unsigned short*)Cout)[(size_t)row * N + col] = f2bf(v);
            }
}

// ---------------- 128x128 GEMM, v5 phase structure (for gemm2), R17-verified ----------------
template<int OUTF32>
__global__ __launch_bounds__(256, 2) void k_gemm128(const unsigned short* __restrict__ A,
                                                    const unsigned short* __restrict__ Bt,
                                                    void* __restrict__ Cout,
                                                    int M, int N, int K) {
    __shared__ unsigned short Ls[2][2][2][4096];   // [slot][mat][kk][128*32] = 64 KiB
    int tid = threadIdx.x, lane = tid & 63, wave = tid >> 6;
    int wm = wave >> 1, wn = wave & 1;
    int lr = lane & 15, lg = lane >> 4;
    int swrow = wave * 16 + (lane >> 2);
    int scol  = (((lane & 3) ^ ((lane >> 3) & 3)) * 8);
    int cg    = ((lg ^ ((lr >> 1) & 3)) * 8);
    const unsigned short* Ab = A  + (size_t)(blockIdx.x * 128) * K;
    const unsigned short* Bb = Bt + (size_t)(blockIdx.y * 128) * K;

    f32x4 acc[4][4] = {};
    int NK = K / 64;

    auto issue = [&](int slot, int mat, int kk, int k0) {
        const unsigned short* base = mat ? Bb : Ab;
        unsigned short* dst = &Ls[slot][mat][kk][wave * 512];
        GLL16(base + (size_t)swrow * K + k0 + kk * 32 + scol, dst);
        GLL16(base + (size_t)(swrow + 64) * K + k0 + kk * 32 + scol, dst + 2048);
    };

    issue(0, 0, 0, 0);
    issue(0, 1, 0, 0);
    issue(0, 0, 1, 0);
    issue(0, 1, 1, 0);
    asm volatile("s_waitcnt vmcnt(4)" ::: "memory");
    __builtin_amdgcn_s_barrier();

    for (int t = 0; t < NK; ++t) {
        int slot = t & 1, nslot = slot ^ 1;
        int kn = (t + 1) * 64;
        bool more = (t + 1) < NK;
        const unsigned short* As0 = Ls[slot][0][0];
        const unsigned short* Bs0 = Ls[slot][1][0];
        const unsigned short* As1 = Ls[slot][0][1];
        const unsigned short* Bs1 = Ls[slot][1][1];
        s16x8 af[4], bfr[4];

        // ---- phase 0: kk0 (certified). Issue kk0(t+1); vmcnt certifies kk1(t). ----
        #pragma unroll
        for (int m = 0; m < 4; m++) af[m]  = *(const s16x8*)&As0[(wm * 64 + m * 16 + lr) * 32 + cg];
        #pragma unroll
        for (int n = 0; n < 4; n++) bfr[n] = *(const s16x8*)&Bs0[(wn * 64 + n * 16 + lr) * 32 + cg];
        if (more) { issue(nslot, 0, 0, kn); issue(nslot, 1, 0, kn);
                    asm volatile("s_waitcnt vmcnt(4)" ::: "memory"); }
        else      { asm volatile("s_waitcnt vmcnt(0)" ::: "memory"); }
        asm volatile("" ::: "memory");
        __builtin_amdgcn_s_barrier();
        __builtin_amdgcn_s_setprio(1);
        #pragma unroll
        for (int m = 0; m < 4; m++)
            #pragma unroll
            for (int n = 0; n < 4; n++)
                acc[m][n] = __builtin_amdgcn_mfma_f32_16x16x32_bf16(af[m], bfr[n], acc[m][n], 0, 0, 0);
        __builtin_amdgcn_s_setprio(0);
        asm volatile("" ::: "memory");
        __builtin_amdgcn_s_barrier();

        // ---- phase 1: kk1 (certified by ph0). Issue kk1(t+1); vmcnt certifies kk0(t+1). ----
        #pragma unroll
        for (int m = 0; m < 4; m++) af[m]  = *(const s16x8*)&As1[(wm * 64 + m * 16 + lr) * 32 + cg];
        #pragma unroll
        for (int n = 0; n < 4; n++) bfr[n] = *(const s16x8*)&Bs1[(wn * 64 + n * 16 + lr) * 32 + cg];
        if (more) { issue(nslot, 0, 1, kn); issue(nslot, 1, 1, kn);
                    asm volatile("s_waitcnt vmcnt(4)" ::: "memory"); }
        asm volatile("" ::: "memory");
        __builtin_amdgcn_s_barrier();
        __builtin_amdgcn_s_setprio(1);
        #pragma unroll
        for (int m = 0; m < 4; m++)
            #pragma unroll
            for (int n = 0; n < 4; n++)
                acc[m][n] = __builtin_amdgcn_mfma_f32_16x16x32_bf16(af[m], bfr[n], acc[m][n], 0, 0, 0);
        __builtin_amdgcn_s_setprio(0);
        asm volatile("" ::: "memory");
        __builtin_amdgcn_s_barrier();
    }

    int rbase = blockIdx.x * 128 + wm * 64;
    int cbase = blockIdx.y * 128 + wn * 64;
    #pragma unroll
    for (int m = 0; m < 4; m++)
        #pragma unroll
        for (int n = 0; n < 4; n++)
            #pragma unroll
            for (int r = 0; r < 4; r++) {
                int row = rbase + m * 16 + lg * 4 + r;
                int col = cbase + n * 16 + lr;
                float v = acc[m][n][r];
                if (OUTF32) ((float*)Cout)[(size_t)row * N + col] = v;
                else        ((unsigned short*)Cout)[(size_t)row * N + col] = f2bf(v);
            }
}

// ---------------- fused post-GEMM: RMSNorm+RoPE (bid<4096) + V transpose (bid>=4096) ----------------
__global__ __launch_bounds__(256) void k_post(const unsigned short* __restrict__ qkv,
                                              const float* __restrict__ qg,
                                              const float* __restrict__ kg,
                                              const float* __restrict__ cosc,
                                              const float* __restrict__ sinc,
                                              unsigned short* __restrict__ Qt,
                                              unsigned short* __restrict__ Kt,
                                              unsigned short* __restrict__ Vtg) {
    __shared__ unsigned short tt[64][65];
    int bid = blockIdx.x;
    int tid = threadIdx.x;
    if (bid >= 4096) {   // V transpose: qkv cols [3072+kvh*128, +128) -> Vtg [d][s]
        int b2 = bid - 4096;                // 0..1023
        int sx = b2 & 31;                   // s-tile
        int rest = b2 >> 5;
        int dy = rest & 1;                  // d-tile
        int bkv = rest >> 1;                // b*8+kvh
        int s0 = sx * 64, d0 = dy * 64;
        int b = bkv >> 3, kvh = bkv & 7;
        const unsigned short* src = qkv + (size_t)(b * 2048) * 4096 + 3072 + kvh * 128;
        unsigned short* dst = Vtg + (size_t)bkv * 128 * 2048;
        int tx = tid & 63, ty0 = tid >> 6;
        #pragma unroll
        for (int p = 0; p < 16; p++) {
            int ty = ty0 + p * 4;
            tt[ty][tx] = src[(size_t)(s0 + ty) * 4096 + d0 + tx];
        }
        __syncthreads();
        #pragma unroll
        for (int p = 0; p < 16; p++) {
            int ty = ty0 + p * 4;
            dst[(size_t)(d0 + ty) * 2048 + s0 + tx] = tt[tx][ty];   // 128B rows
        }
        return;
    }
    int r = bid;                   // b*2048 + s
    int b = r >> 11;
    int s = r & 2047;
    int wave = tid >> 6, lane = tid & 63;
    int sl = lane >> 4;            // local segment 0..3
    int li = lane & 15;
    int d0 = li * 8;               // 0..120
    const unsigned short* row = qkv + (size_t)r * 4096;
    #pragma unroll
    for (int p = 0; p < 2; p++) {
        int seg = p * 16 + wave * 4 + sl;   // 0..31, wave-uniform
        if (seg >= 24) continue;            // V handled by transpose path
        s16x8 raw = *(const s16x8*)(row + seg * 128 + d0);
        float e[8];
        #pragma unroll
        for (int j = 0; j < 8; j++) e[j] = bf2f((unsigned short)raw[j]);
        float ssq = 0.f;
        #pragma unroll
        for (int j = 0; j < 8; j++) ssq += e[j] * e[j];
        ssq += __shfl_xor(ssq, 1, 64);
        ssq += __shfl_xor(ssq, 2, 64);
        ssq += __shfl_xor(ssq, 4, 64);
        ssq += __shfl_xor(ssq, 8, 64);
        float rn = rsqrtf(ssq * (1.0f / 128.0f) + 1e-6f);
        const float* g = (seg < 16) ? qg : kg;
        float gs = (seg < 16) ? SCALE_L2E : 1.0f;
        float4 g0 = *(const float4*)(g + d0);
        float4 g1 = *(const float4*)(g + d0 + 4);
        float t[8];
        t[0] = e[0] * rn * g0.x * gs; t[1] = e[1] * rn * g0.y * gs;
        t[2] = e[2] * rn * g0.z * gs; t[3] = e[3] * rn * g0.w * gs;
        t[4] = e[4] * rn * g1.x * gs; t[5] = e[5] * rn * g1.y * gs;
        t[6] = e[6] * rn * g1.z * gs; t[7] = e[7] * rn * g1.w * gs;
        float pr[8];
        #pragma unroll
        for (int j = 0; j < 8; j++) pr[j] = __shfl_xor(t[j], 8, 64);
        int didx = d0 & 63;
        float4 c0 = *(const float4*)(cosc + (size_t)s * 64 + didx);
        float4 c1 = *(const float4*)(cosc + (size_t)s * 64 + didx + 4);
        float4 sn0 = *(const float4*)(sinc + (size_t)s * 64 + didx);
        float4 sn1 = *(const float4*)(sinc + (size_t)s * 64 + didx + 4);
        float cv[8] = {c0.x, c0.y, c0.z, c0.w, c1.x, c1.y, c1.z, c1.w};
        float sv[8] = {sn0.x, sn0.y, sn0.z, sn0.w, sn1.x, sn1.y, sn1.z, sn1.w};
        float sgn = (li < 8) ? -1.0f : 1.0f;
        s16x8 o;
        #pragma unroll
        for (int j = 0; j < 8; j++)
            o[j] = (short)f2bf(t[j] * cv[j] + sgn * pr[j] * sv[j]);
        unsigned short* dst = (seg < 16)
            ? Qt + ((size_t)(b * 16 + seg) * 2048 + s) * 128 + d0
            : Kt + ((size_t)(b * 8 + (seg - 16)) * 2048 + s) * 128 + d0;
        *(s16x8*)dst = o;
    }
}

// ---------------- causal GQA flash attention: dbuf K/V + in-register P (R18/R21, measured best) ----------------
__global__ __launch_bounds__(256, 2) void k_attn(const unsigned short* __restrict__ Qt,
                                                 const unsigned short* __restrict__ Kt,
                                                 const unsigned short* __restrict__ Vtg,
                                                 unsigned short* __restrict__ attn) {
    __shared__ unsigned short Ks[2][64 * 128];   // [buf][kv][d] swizzled  32 KiB
    __shared__ unsigned short Vs[2][128 * 64];   // [buf][d][kv] swizzled  32 KiB
    int bid = blockIdx.x;                  // 0..511
    int lo = bid & 255;
    int qb, bh;
    if (bid < 256) { qb = lo & 15;        bh = lo >> 4; }
    else           { qb = 15 - (lo & 15); bh = 16 + (lo >> 4); }
    int b = bh >> 4, h = bh & 15;
    int kvh = h >> 1;
    int tid = threadIdx.x;
    int lane = tid & 63, wave = tid >> 6;
    int ql = lane & 31;                    // q-local (wave's 32 rows)
    int hf = lane >> 5;                    // half 0/1
    int q0 = qb * 128;
    const unsigned short* Qb    = Qt + ((size_t)bh * 2048 + q0 + wave * 32 + ql) * 128;
    const unsigned short* Kbase = Kt + (size_t)(b * 8 + kvh) * 2048 * 128;
    const unsigned short* Vtb   = Vtg + (size_t)(b * 8 + kvh) * 128 * 2048;   // [d][s]
    s16x8 aq[8];
    #pragma unroll
    for (int ds = 0; ds < 8; ds++)
        aq[ds] = *(const s16x8*)(Qb + ds * 16 + hf * 8);
    f32x16 out[4] = {};
    float m_q = -1e30f, l_q = 0.f;
    int qglob = q0 + wave * 32 + ql;
    int qlo   = q0 + wave * 32;            // wave-uniform bounds
    int qhi   = qlo + 31;
    int ntiles = 2 * qb + 2;
    int krow = tid >> 4, kcolb = tid & 15;   // K: 16 rows x 16 slots per pass
    int vrow = tid >> 3, vcolb = tid & 7;    // V^T: 32 rows x 8 slots per pass
    int ksw = kcolb ^ (krow & 7);
    int vsw = vcolb ^ (vrow & 7);
    int eq = (ql & 7);
    s16x8 kpre[4], vpre[4];
    #pragma unroll
    for (int p = 0; p < 4; p++) {
        kpre[p] = *(const s16x8*)(Kbase + (size_t)(krow + p * 16) * 128 + kcolb * 8);
        vpre[p] = *(const s16x8*)(Vtb + (size_t)(vrow + p * 32) * 2048 + vcolb * 8);
    }

    for (int t = 0; t < ntiles; t++) {
        int k0 = t * 64;
        int buf = t & 1;
        #pragma unroll
        for (int p = 0; p < 4; p++) {
            *(s16x8*)&Ks[buf][(krow + p * 16) * 128 + ksw * 8] = kpre[p];
            *(s16x8*)&Vs[buf][(vrow + p * 32) * 64  + vsw * 8] = vpre[p];
        }
        __syncthreads();
        if (t + 1 < ntiles) {
            int kn = k0 + 64;
            #pragma unroll
            for (int p = 0; p < 4; p++) {
                kpre[p] = *(const s16x8*)(Kbase + (size_t)(kn + krow + p * 16) * 128 + kcolb * 8);
                vpre[p] = *(const s16x8*)(Vtb + (size_t)(vrow + p * 32) * 2048 + kn + vcolb * 8);
            }
        }
        if (k0 <= qhi) {
            f32x16 st[2] = {};
            __builtin_amdgcn_s_setprio(1);
            #pragma unroll
            for (int sub = 0; sub < 2; sub++)
                #pragma unroll
                for (int ds = 0; ds < 8; ds++) {
                    s16x8 kf = *(const s16x8*)&Ks[buf][(sub * 32 + ql) * 128 + ((ds * 2 + hf) ^ eq) * 8];
                    st[sub] = __builtin_amdgcn_mfma_f32_32x32x16_bf16(kf, aq[ds], st[sub], 0, 0, 0);
                }
            __builtin_amdgcn_s_setprio(0);
            float mx = -1e30f;
            if (k0 + 63 > qlo) {
                #pragma unroll
                for (int sub = 0; sub < 2; sub++)
                    #pragma unroll
                    for (int r = 0; r < 16; r++) {
                        int kv = k0 + sub * 32 + (r & 3) + 8 * (r >> 2) + 4 * hf;
                        if (kv > qglob) st[sub][r] = -1e30f;
                        mx = fmaxf(mx, st[sub][r]);
                    }
            } else {
                #pragma unroll
                for (int sub = 0; sub < 2; sub++)
                    #pragma unroll
                    for (int r = 0; r < 16; r++) mx = fmaxf(mx, st[sub][r]);
            }
            mx = fmaxf(mx, __shfl_xor(mx, 32, 64));
            bool defer = __all(mx <= m_q + 8.0f);
            float sf = 1.0f;
            if (!defer) {
                float mnew = fmaxf(m_q, mx);
                sf = exp2_fast(m_q - mnew);
                m_q = mnew;
            }
            float rs = 0.f;
            #pragma unroll
            for (int sub = 0; sub < 2; sub++)
                #pragma unroll
                for (int r = 0; r < 16; r++) {
                    float e = exp2_fast(st[sub][r] - m_q);
                    st[sub][r] = e;
                    rs += e;
                }
            rs += __shfl_xor(rs, 32, 64);
            l_q = defer ? (l_q + rs) : (l_q * sf + rs);
            // in-register P fragments: cvt_pk + permlane32_swap (T12)
            s16x8 pf[4];
            #pragma unroll
            for (int sub = 0; sub < 2; sub++) {
                unsigned w0a = cvt_pk_bf16(st[sub][0],  st[sub][1]);
                unsigned w0b = cvt_pk_bf16(st[sub][2],  st[sub][3]);
                unsigned w1a = cvt_pk_bf16(st[sub][4],  st[sub][5]);
                unsigned w1b = cvt_pk_bf16(st[sub][6],  st[sub][7]);
                unsigned w2a = cvt_pk_bf16(st[sub][8],  st[sub][9]);
                unsigned w2b = cvt_pk_bf16(st[sub][10], st[sub][11]);
                unsigned w3a = cvt_pk_bf16(st[sub][12], st[sub][13]);
                unsigned w3b = cvt_pk_bf16(st[sub][14], st[sub][15]);
                auto s0 = __builtin_amdgcn_permlane32_swap(w0a, w1a, false, false);
                auto s1 = __builtin_amdgcn_permlane32_swap(w0b, w1b, false, false);
                auto s2 = __builtin_amdgcn_permlane32_swap(w2a, w3a, false, false);
                auto s3 = __builtin_amdgcn_permlane32_swap(w2b, w3b, false, false);
                union { unsigned u[4]; s16x8 v; } fa, fb;
                fa.u[0] = s0[0]; fa.u[1] = s1[0]; fa.u[2] = s0[1]; fa.u[3] = s1[1];
                fb.u[0] = s2[0]; fb.u[1] = s3[0]; fb.u[2] = s2[1]; fb.u[3] = s3[1];
                pf[sub * 2]     = fa.v;
                pf[sub * 2 + 1] = fb.v;
            }
            if (!defer) {
                float sfr[16];
                #pragma unroll
                for (int r = 0; r < 16; r++)
                    sfr[r] = __shfl(sf, (r & 3) + 8 * (r >> 2) + 4 * hf, 64);
                #pragma unroll
                for (int dblk = 0; dblk < 4; dblk++)
                    #pragma unroll
                    for (int r = 0; r < 16; r++) out[dblk][r] *= sfr[r];
            }
            __builtin_amdgcn_s_setprio(1);
            #pragma unroll
            for (int ks = 0; ks < 4; ks++) {
                #pragma unroll
                for (int dblk = 0; dblk < 4; dblk++) {
                    s16x8 vf = *(const s16x8*)&Vs[buf][(dblk * 32 + ql) * 64 + ((ks * 2 + hf) ^ eq) * 8];
                    out[dblk] = __builtin_amdgcn_mfma_f32_32x32x16_bf16(pf[ks], vf, out[dblk], 0, 0, 0);
                }
            }
            __builtin_amdgcn_s_setprio(0);
        }
    }
    float linv = 1.0f / l_q;
    float inv[16];
    #pragma unroll
    for (int r = 0; r < 16; r++)
        inv[r] = __shfl(linv, (r & 3) + 8 * (r >> 2) + 4 * hf, 64);
    #pragma unroll
    for (int dblk = 0; dblk < 4; dblk++)
        #pragma unroll
        for (int r = 0; r < 16; r++) {
            int row = q0 + wave * 32 + (r & 3) + 8 * (r >> 2) + 4 * hf;
            attn[((size_t)(b * 2048) + row) * 2048 + h * 128 + dblk * 32 + ql] =
                f2bf(out[dblk][r] * inv[r]);
        }
}

extern "C" void kernel_launch(void* const* d_in, const int* in_sizes, int n_in,
                              void* d_out, int out_size, void* d_ws, size_t ws_size,
                              hipStream_t stream) {
    const float* x    = (const float*)d_in[0];
    const float* wq   = (const float*)d_in[1];
    const float* wk   = (const float*)d_in[2];
    const float* wv   = (const float*)d_in[3];
    const float* wo   = (const float*)d_in[4];
    const float* qg   = (const float*)d_in[5];
    const float* kg   = (const float*)d_in[6];
    const float* cosc = (const float*)d_in[7];
    const float* sinc = (const float*)d_in[8];

    char* ws = (char*)d_ws;
    unsigned short* xb   = (unsigned short*)(ws);                 // 16 MiB  x bf16 (4096x2048)
    unsigned short* w1t  = (unsigned short*)(ws + 16777216);      // 16 MiB  [wq|wk|wv]^T (4096x2048)
    unsigned short* w2t  = (unsigned short*)(ws + 33554432);      //  8 MiB  wo^T (2048x2048)
    unsigned short* qkv  = (unsigned short*)(ws + 41943040);      // 32 MiB  (4096x4096)
    unsigned short* Qt   = (unsigned short*)(ws + 75497472);      // 16 MiB  (2,16,2048,128)
    unsigned short* Kt   = (unsigned short*)(ws + 92274688);      //  8 MiB  (2,8,2048,128)
    unsigned short* Vtg  = (unsigned short*)(ws + 100663296);     //  8 MiB  (2,8,128,2048)
    unsigned short* attn = (unsigned short*)(ws + 109051904);     // 16 MiB  (4096x2048)

    k_prep<<<dim3(32, 32, 5), 256, 0, stream>>>(x, wq, wk, wv, wo, xb, w1t, w2t);
    k_gemm256<0><<<dim3(16, 16), 512, 0, stream>>>(xb, w1t, qkv, 4096, 4096, 2048);
    k_post<<<5120, 256, 0, stream>>>(qkv, qg, kg, cosc, sinc, Qt, Kt, Vtg);
    k_attn<<<512, 256, 0, stream>>>(Qt, Kt, Vtg, attn);
    k_gemm128<1><<<dim3(32, 16), 256, 0, stream>>>(attn, w2t, d_out, 4096, 2048, 2048);
}